// Round 10
// baseline (261.031 us; speedup 1.0000x reference)
//
#include <hip/hip_runtime.h>
#include <math.h>

#define NB 4
#define NP 8192
#define KK 16
#define QPB 64
#define NPTS (NB * NP)

// ---- geometry (round 10) ----
#define TSAMP 2048            // tau sample = candidates [0,2048)
#define TNTS 16               // tau: 16 sub-waves per query-group
#define TTCH 128              // tau subchunk per wave (2048/16)
#define BCH 1024              // filter chunk size (R5/R7/R8 proven zero-overflow)
#define NBCH 8                // 8 chunks cover [0,8192)
#define CAP 30                // per-(query,chunk) capacity (proven geometry)
#define SROW 34               // u16 per (chunk,query) LDS row: [0]=cnt,[1..30]=idx(+pad)
#define SCH (64 * SROW + 2)   // LDS chunk stride in u16
#define TAU_MARGIN 2.5e-4f    // >= 7x the |fast_d2-ref_d2| bound (~3.4e-5)

// Correctness chain:
//  tau_ref = EXACT 16th-smallest ref-dist over [0,2048)  (any tau bug is
//  harmless: fail-safe below).  Filter keeps {fast_d <= tau_ref + MARGIN}
//  which is a superset of {ref_d <= tau_ref} (|fast-ref| <= 3.4e-5), which
//  contains the exact top-16.  Select re-ranks the survivor stream
//  (ascending global index) with the PROVEN exact insertion chain by
//  ref-dist -> identical top-16, distance-sorted order == lax.top_k gather
//  order (absmax 0.0 measured R6-R9).  Any chunk count > CAP or total < 16
//  => proven exact full-scan for that query.

// comparator macros (exact: min/max introduce no rounding)
#define CSWAP_DESC(a, b) { float _lo = fminf(a, b); float _hi = fmaxf(a, b); a = _hi; b = _lo; }
#define CSWAP_ASC(a, b)  { float _lo = fminf(a, b); float _hi = fmaxf(a, b); a = _lo; b = _hi; }

// reference-rounded |p|^2 : (xx+yy)+zz
__device__ __forceinline__ float ref_sq(float x, float y, float z) {
  return __fadd_rn(__fadd_rn(__fmul_rn(x, x), __fmul_rn(y, y)), __fmul_rn(z, z));
}

// reference-rounded d2 = (sqq + sqc) - 2*dot, dot = (xx+yy)+zz
__device__ __forceinline__ float ref_d2q(float qx, float qy, float qz, float sqq,
                                         float4 c) {
  float dot = __fadd_rn(__fadd_rn(__fmul_rn(qx, c.x), __fmul_rn(qy, c.y)),
                        __fmul_rn(qz, c.z));
  float s = __fadd_rn(sqq, c.w);
  return __fmaf_rn(-2.0f, dot, s);
}

// fast 5-op distance (fma dot); |fast - ref| <= ~3.4e-5 on this data range.
// Used ONLY for the filter compare against tau_ref + TAU_MARGIN.
__device__ __forceinline__ float fast_d2(float qx, float qy, float qz, float sqq,
                                         float4 c) {
  float dot = __fmaf_rn(qz, c.z, __fmaf_rn(qy, c.y, __fmul_rn(qx, c.x)));
  float s = __fadd_rn(sqq, c.w);
  return __fmaf_rn(-2.0f, dot, s);
}

// batched top-16 update: 8 new distances d[0..7] vs sorted-asc bd[0..15]
__device__ __forceinline__ void topk_update(float bd[KK], float d[8]) {
  CSWAP_DESC(d[0], d[1]) CSWAP_DESC(d[2], d[3]) CSWAP_DESC(d[4], d[5]) CSWAP_DESC(d[6], d[7])
  CSWAP_DESC(d[0], d[2]) CSWAP_DESC(d[1], d[3]) CSWAP_DESC(d[4], d[6]) CSWAP_DESC(d[5], d[7])
  CSWAP_DESC(d[1], d[2]) CSWAP_DESC(d[5], d[6])
  CSWAP_DESC(d[0], d[4]) CSWAP_DESC(d[1], d[5]) CSWAP_DESC(d[2], d[6]) CSWAP_DESC(d[3], d[7])
  CSWAP_DESC(d[2], d[4]) CSWAP_DESC(d[3], d[5])
  CSWAP_DESC(d[1], d[2]) CSWAP_DESC(d[3], d[4]) CSWAP_DESC(d[5], d[6])
#pragma unroll
  for (int i = 0; i < 8; ++i) bd[8 + i] = fminf(bd[8 + i], d[i]);
#pragma unroll
  for (int i = 0; i < 8; ++i)  CSWAP_ASC(bd[i], bd[i + 8])
#pragma unroll
  for (int i = 0; i < 4; ++i)  CSWAP_ASC(bd[i], bd[i + 4])
#pragma unroll
  for (int i = 8; i < 12; ++i) CSWAP_ASC(bd[i], bd[i + 4])
#pragma unroll
  for (int g = 0; g < 4; ++g) {
    CSWAP_ASC(bd[4 * g + 0], bd[4 * g + 2]) CSWAP_ASC(bd[4 * g + 1], bd[4 * g + 3])
    CSWAP_ASC(bd[4 * g + 0], bd[4 * g + 1]) CSWAP_ASC(bd[4 * g + 2], bd[4 * g + 3])
  }
}

__global__ void prep_kernel(const float* __restrict__ x,
                            float4* __restrict__ cand) {
  int i = blockIdx.x * 256 + threadIdx.x;
  if (i < NPTS) {
    float px = x[3 * i + 0], py = x[3 * i + 1], pz = x[3 * i + 2];
    cand[i] = make_float4(px, py, pz, ref_sq(px, py, pz));
  }
}

// ---------------- kA: tau = exact 16th-smallest ref-dist over [0,2048) ------
// Round 10: 16 sub-waves per group, 1024-thread blocks, dynamic 69.6KB LDS,
// log2 tree merge. 8192 waves, 2 blocks/CU -> 32 waves/CU (R9 was 16/CU).
// tau errors are harmless (fail-safe): this stage only affects speed.
__global__ __launch_bounds__(1024) void tau_stage_kernel(
    const float4* __restrict__ cand, float* __restrict__ tauArr) {
  extern __shared__ __align__(16) char smem[];
  float4* samp = (float4*)smem;                    // [2048] (32KB), phases 1-2
  float (*s_t)[64][17] = (float (*)[64][17])smem;  // [16][64][17] (69.6KB) 3-4
  const int tid   = threadIdx.x;
  const int lane  = tid & 63;
  const int w     = __builtin_amdgcn_readfirstlane(tid >> 6);  // 0..15
  const int group = blockIdx.x;              // 0..511
  const int batch = group >> 7;
  const int qbase = (group & 127) * QPB;
  const float4* __restrict__ Cb = cand + (size_t)batch * NP;

  const float4 q = Cb[qbase + lane];
  const float qx = q.x, qy = q.y, qz = q.z, sqq = q.w;

  // phase 1: cooperative stage of sample [0,2048) -- coalesced dwordx4
#pragma unroll
  for (int r = 0; r < TSAMP / 1024; ++r)
    samp[r * 1024 + tid] = Cb[r * 1024 + tid];
  __syncthreads();

  // phase 2: scan own 128-candidate subchunk from LDS (verbatim body)
  float bd[KK];
#pragma unroll
  for (int t = 0; t < KK; ++t) bd[t] = 3.4e38f;

  const int j0 = w * TTCH;
  for (int jj = 0; jj < TTCH; jj += 8) {
    const float4* xp = samp + (j0 + jj);     // uniform LDS addr: broadcast
    float4 c[8];
#pragma unroll
    for (int u = 0; u < 8; ++u) c[u] = xp[u];
    float d[8];
#pragma unroll
    for (int u = 0; u < 8; ++u) d[u] = ref_d2q(qx, qy, qz, sqq, c[u]);
    topk_update(bd, d);
  }
  __syncthreads();                           // all done reading samp

  // phase 3: publish sorted sub-lists (overlays samp region)
#pragma unroll
  for (int t = 0; t < KK; ++t) s_t[w][lane][t] = bd[t];
  __syncthreads();

  // phase 4: log2 tree merge (4 steps). Active waves halve each step.
  float md[KK];
#pragma unroll
  for (int t = 0; t < KK; ++t) md[t] = bd[t];
#pragma unroll
  for (int dstep = 1; dstep < TNTS; dstep <<= 1) {
    if ((w & (2 * dstep - 1)) == 0) {        // wave-uniform branch
      float dd[KK];
#pragma unroll
      for (int t = 0; t < KK; ++t) dd[t] = s_t[w + dstep][lane][t];
      topk_update(md, &dd[0]);
      topk_update(md, &dd[8]);
#pragma unroll
      for (int t = 0; t < KK; ++t) s_t[w][lane][t] = md[t];
    }
    __syncthreads();
  }
  if (w == 0) tauArr[batch * NP + qbase + lane] = md[KK - 1];
}

// ---------------- kB: fused filter + select + eigen -------------------------
// Block = query-group (64 queries), 8 waves; wave w scans chunk w with the
// PROVEN 16-wide batched body (fast_d2 vs tau_ref+MARGIN: superset filter).
// Survivor indices stay in LDS; after the barrier, wave 0 (one thread per
// query) runs the PROVEN exact chain + eigen directly from LDS and writes
// out. No rec buffer, no compaction, no third kernel.
__global__ __launch_bounds__(512) void filter_select_kernel(
    const float4* __restrict__ cand, const float* __restrict__ tauArr,
    float* __restrict__ out) {
  __shared__ unsigned short s_idx[NBCH * SCH];   // 34,848 B
  const int tid   = threadIdx.x;
  const int lane  = tid & 63;
  const int w     = __builtin_amdgcn_readfirstlane(tid >> 6);
  const int group = blockIdx.x;              // 0..511
  const int batch = group >> 7;
  const int qbase = (group & 127) * QPB;
  const int j0    = w * BCH;
  const float4* __restrict__ Cb = cand + (size_t)batch * NP;

  // ---- filter phase (R8-proven structure; fast_d2 + margined tau) ----
  {
    const float tauf = tauArr[batch * NP + qbase + lane] + TAU_MARGIN;
    const float4 q = Cb[qbase + lane];
    const float qx = q.x, qy = q.y, qz = q.z, sqq = q.w;

    unsigned short* Srow = &s_idx[w * SCH + lane * SROW];
    int cnt = 0;
    for (int jj = 0; jj < BCH; jj += 16) {
      const float4* xp = Cb + (j0 + jj);     // wave-uniform address
      float4 c[16];
#pragma unroll
      for (int u = 0; u < 16; ++u) c[u] = xp[u];   // 16 loads in flight
#pragma unroll
      for (int u = 0; u < 16; ++u) {
        float d = fast_d2(qx, qy, qz, sqq, c[u]);
        if (d <= tauf) {
          if (cnt < CAP) Srow[1 + cnt] = (unsigned short)(j0 + jj + u);
          ++cnt;                             // count ALL survivors
        }
      }
    }
    Srow[0] = (unsigned short)cnt;
  }
  __syncthreads();

  // ---- select + eigen phase: wave 0, one query per thread ----
  if (tid < QPB) {
    const int ql = tid;
    const int qg = batch * NP + qbase + ql;
    const float4 qq = Cb[qbase + ql];
    const float q2x = qq.x, q2y = qq.y, q2z = qq.z, sq2 = qq.w;

    int cns[NBCH];
    int total = 0;
    bool fs = false;
#pragma unroll
    for (int ch = 0; ch < NBCH; ++ch) {
      cns[ch] = (int)s_idx[ch * SCH + ql * SROW];
      if (cns[ch] > CAP) fs = true;          // overflow -> full scan
      total += cns[ch];
    }
    if (total < KK) fs = true;               // tau anomaly -> full scan

    float md[KK]; int mjr[KK];
#pragma unroll
    for (int t = 0; t < KK; ++t) { md[t] = 3.4e38f; mjr[t] = 0; }

    if (!fs) {
      // stream survivors: chunk asc, entry asc (== proven R8 stream order).
      // 8-wide batches: 8 LDS index reads + 8 gathers in flight, +inf pad.
      for (int ch = 0; ch < NBCH; ++ch) {
        const unsigned short* L = &s_idx[ch * SCH + ql * SROW + 1];
        const int cn = cns[ch];
        for (int e = 0; e < cn; e += 8) {
          int jv[8];
          float dv[8];
#pragma unroll
          for (int u = 0; u < 8; ++u) {
            const bool ok = (e + u) < cn;
            int j = ok ? (int)L[e + u] : 0;  // reads stay inside the row
            j &= (NP - 1);                   // clamp (identity for ok lanes)
            jv[u] = j;
            const float dd = ref_d2q(q2x, q2y, q2z, sq2, Cb[j]);
            dv[u] = ok ? dd : 3.4e38f;       // +inf pad: chain no-op
          }
#pragma unroll
          for (int u = 0; u < 8; ++u) {
            const float d = dv[u];
            const int j = jv[u];
            if (d < md[KK - 1]) {
              bool c0 = d < md[0];
#pragma unroll
              for (int t = KK - 1; t >= 1; --t) {
                bool cl = d < md[t];
                bool cp = d < md[t - 1];
                float nv = fmaxf(md[t - 1], fminf(md[t], d));
                mjr[t] = cl ? (cp ? mjr[t - 1] : j) : mjr[t];
                md[t] = nv;
              }
              mjr[0] = c0 ? j : mjr[0];
              md[0] = fminf(md[0], d);
            }
          }
        }
      }
    } else {
      // exact full-scan insertion with index tracking (verbatim-proven)
      for (int j = 0; j < NP; ++j) {
        float d = ref_d2q(q2x, q2y, q2z, sq2, Cb[j]);
        if (d < md[KK - 1]) {
          bool c0 = d < md[0];
#pragma unroll
          for (int t = KK - 1; t >= 1; --t) {
            bool cl = d < md[t];
            bool cp = d < md[t - 1];
            float nv = fmaxf(md[t - 1], fminf(md[t], d));
            mjr[t] = cl ? (cp ? mjr[t - 1] : j) : mjr[t];
            md[t] = nv;
          }
          mjr[0] = c0 ? j : mjr[0];
          md[0] = fminf(md[0], d);
        }
      }
    }

    // ---- covariance + eigen tail (verbatim-verified arithmetic, R8 form)
    float sx = 0.f, sy = 0.f, sz = 0.f;
#pragma unroll
    for (int s = 0; s < KK; ++s) {
      float4 pp = Cb[mjr[s]];
      sx = __fadd_rn(sx, pp.x);
      sy = __fadd_rn(sy, pp.y);
      sz = __fadd_rn(sz, pp.z);
    }
    const float k1 = 1.0f / KK;   // exact power of two
    const float mx = sx * k1, my = sy * k1, mz = sz * k1;

    float cxx = 0.f, cxy = 0.f, cxz = 0.f, cyy = 0.f, cyz = 0.f, czz = 0.f;
#pragma unroll
    for (int s = 0; s < KK; ++s) {
      float4 pp = Cb[mjr[s]];
      float dx = __fsub_rn(pp.x, mx);
      float dy = __fsub_rn(pp.y, my);
      float dz = __fsub_rn(pp.z, mz);
      cxx = __fadd_rn(cxx, __fmul_rn(dx, dx));
      cxy = __fadd_rn(cxy, __fmul_rn(dx, dy));
      cxz = __fadd_rn(cxz, __fmul_rn(dx, dz));
      cyy = __fadd_rn(cyy, __fmul_rn(dy, dy));
      cyz = __fadd_rn(cyz, __fmul_rn(dy, dz));
      czz = __fadd_rn(czz, __fmul_rn(dz, dz));
    }

    double a   = (double)__fmul_rn(cxx, k1), b = (double)__fmul_rn(cyy, k1);
    double c2  = (double)__fmul_rn(czz, k1);
    double dxy = (double)__fmul_rn(cxy, k1), exz = (double)__fmul_rn(cxz, k1);
    double fyz = (double)__fmul_rn(cyz, k1);
    double qm = (a + b + c2) / 3.0;
    double p1 = dxy * dxy + exz * exz + fyz * fyz;
    double aa = a - qm, bb = b - qm, cc = c2 - qm;
    double p2 = aa * aa + bb * bb + cc * cc + 2.0 * p1;
    double ratio;
    if (p2 <= 0.0) {
      ratio = 1.0;
    } else {
      double p  = sqrt(p2 / 6.0);
      double ip = 1.0 / p;
      double b00 = aa * ip, b11 = bb * ip, b22 = cc * ip;
      double b01 = dxy * ip, b02 = exz * ip, b12 = fyz * ip;
      double detB = b00 * (b11 * b22 - b12 * b12)
                  - b01 * (b01 * b22 - b12 * b02)
                  + b02 * (b01 * b12 - b11 * b02);
      double r = 0.5 * detB;
      r = fmin(1.0, fmax(-1.0, r));
      double phi = acos(r) / 3.0;
      double e0 = qm + 2.0 * p * cos(phi);                      // largest
      double e2 = qm + 2.0 * p * cos(phi + 2.0943951023931954); // smallest
      double e1 = 3.0 * qm - e0 - e2;                           // middle
      ratio = e0 / e1;
    }
    out[qg] = (float)ratio;
  }
}

// ---------------- fallback: verbatim single kernel (proven pass) ------------
__global__ __launch_bounds__(512, 4) void knn_eigen_fallback(
    const float4* __restrict__ cand, float* __restrict__ out) {
  __shared__ unsigned short s_j[8][QPB][18];

  const int tid   = threadIdx.x;
  const int lane  = tid & 63;
  const int w     = __builtin_amdgcn_readfirstlane(tid >> 6);
  const int batch = blockIdx.x >> 7;
  const int qbase = (blockIdx.x & 127) * QPB;
  const int FCH   = NP / 8;   // 1024

  const float4* __restrict__ Cb = cand + (size_t)batch * NP;

  const float4 q = Cb[qbase + lane];
  const float qx = q.x, qy = q.y, qz = q.z, sqq = q.w;

  float bd[KK];
#pragma unroll
  for (int t = 0; t < KK; ++t) bd[t] = 3.4e38f;

  const int j0 = w * FCH;
  for (int jj = 0; jj < FCH; jj += 8) {
    const float4* xp = Cb + (j0 + jj);
    float4 c[8];
#pragma unroll
    for (int u = 0; u < 8; ++u) c[u] = xp[u];
    float d[8];
#pragma unroll
    for (int u = 0; u < 8; ++u) d[u] = ref_d2q(qx, qy, qz, sqq, c[u]);
    topk_update(bd, d);
  }

  const float T = bd[KK - 1];
  int cnt = 0;
  for (int jj = 0; jj < FCH; jj += 8) {
    const float4* xp = Cb + (j0 + jj);
    float4 c[8];
#pragma unroll
    for (int u = 0; u < 8; ++u) c[u] = xp[u];
#pragma unroll
    for (int u = 0; u < 8; ++u) {
      float d = ref_d2q(qx, qy, qz, sqq, c[u]);
      if (d <= T && cnt < KK) {
        s_j[w][lane][cnt] = (unsigned short)(j0 + jj + u);
        cnt++;
      }
    }
  }
  __syncthreads();

  if (tid < QPB) {
    const float4 qq = Cb[qbase + tid];
    const float q2x = qq.x, q2y = qq.y, q2z = qq.z, sq2 = qq.w;
    float md[KK]; int mj[KK];
#pragma unroll
    for (int t = 0; t < KK; ++t) { md[t] = 3.4e38f; mj[t] = 0; }
    for (int cch = 0; cch < 8; ++cch) {
      const unsigned int* rowp = (const unsigned int*)&s_j[cch][tid][0];
#pragma unroll
      for (int sp = 0; sp < KK / 2; ++sp) {
        unsigned int pk = rowp[sp];
#pragma unroll
        for (int half = 0; half < 2; ++half) {
          int j = (half == 0) ? (int)(pk & 0xFFFFu) : (int)(pk >> 16);
          float d = ref_d2q(q2x, q2y, q2z, sq2, Cb[j]);
          if (d < md[KK - 1]) {
            bool c0 = d < md[0];
#pragma unroll
            for (int t = KK - 1; t >= 1; --t) {
              bool cl = d < md[t];
              bool cp = d < md[t - 1];
              float nv = fmaxf(md[t - 1], fminf(md[t], d));
              mj[t] = cl ? (cp ? mj[t - 1] : j) : mj[t];
              md[t] = nv;
            }
            mj[0] = c0 ? j : mj[0];
            md[0] = fminf(md[0], d);
          }
        }
      }
    }
    float sx = 0.f, sy = 0.f, sz = 0.f;
#pragma unroll
    for (int s = 0; s < KK; ++s) {
      float4 pp = Cb[mj[s]];
      sx = __fadd_rn(sx, pp.x);
      sy = __fadd_rn(sy, pp.y);
      sz = __fadd_rn(sz, pp.z);
    }
    const float k1 = 1.0f / KK;
    const float mx = sx * k1, my = sy * k1, mz = sz * k1;
    float cxx = 0.f, cxy = 0.f, cxz = 0.f, cyy = 0.f, cyz = 0.f, czz = 0.f;
#pragma unroll
    for (int s = 0; s < KK; ++s) {
      float4 pp = Cb[mj[s]];
      float dx = __fsub_rn(pp.x, mx);
      float dy = __fsub_rn(pp.y, my);
      float dz = __fsub_rn(pp.z, mz);
      cxx = __fadd_rn(cxx, __fmul_rn(dx, dx));
      cxy = __fadd_rn(cxy, __fmul_rn(dx, dy));
      cxz = __fadd_rn(cxz, __fmul_rn(dx, dz));
      cyy = __fadd_rn(cyy, __fmul_rn(dy, dy));
      cyz = __fadd_rn(cyz, __fmul_rn(dy, dz));
      czz = __fadd_rn(czz, __fmul_rn(dz, dz));
    }
    double a   = (double)__fmul_rn(cxx, k1), b = (double)__fmul_rn(cyy, k1);
    double c2  = (double)__fmul_rn(czz, k1);
    double dxy = (double)__fmul_rn(cxy, k1), exz = (double)__fmul_rn(cxz, k1);
    double fyz = (double)__fmul_rn(cyz, k1);
    double qm = (a + b + c2) / 3.0;
    double p1 = dxy * dxy + exz * exz + fyz * fyz;
    double aa = a - qm, bb = b - qm, cc = c2 - qm;
    double p2 = aa * aa + bb * bb + cc * cc + 2.0 * p1;
    double ratio;
    if (p2 <= 0.0) {
      ratio = 1.0;
    } else {
      double p  = sqrt(p2 / 6.0);
      double ip = 1.0 / p;
      double b00 = aa * ip, b11 = bb * ip, b22 = cc * ip;
      double b01 = dxy * ip, b02 = exz * ip, b12 = fyz * ip;
      double detB = b00 * (b11 * b22 - b12 * b12)
                  - b01 * (b01 * b22 - b12 * b02)
                  + b02 * (b01 * b12 - b11 * b02);
      double r = 0.5 * detB;
      r = fmin(1.0, fmax(-1.0, r));
      double phi = acos(r) / 3.0;
      double e0 = qm + 2.0 * p * cos(phi);
      double e2 = qm + 2.0 * p * cos(phi + 2.0943951023931954);
      double e1 = 3.0 * qm - e0 - e2;
      ratio = e0 / e1;
    }
    out[(size_t)batch * NP + qbase + tid] = (float)ratio;
  }
}

extern "C" void kernel_launch(void* const* d_in, const int* in_sizes, int n_in,
                              void* d_out, int out_size, void* d_ws, size_t ws_size,
                              hipStream_t stream) {
  const float* x = (const float*)d_in[0];
  float* out = (float*)d_out;
  float4* cand = (float4*)d_ws;                                   // 512 KB
  float* tauArr = (float*)((char*)d_ws + (size_t)NPTS * sizeof(float4)); // 128 KB
  const size_t need = (size_t)NPTS * sizeof(float4) +
                      (size_t)NPTS * sizeof(float);               // 640 KB

  prep_kernel<<<dim3(NPTS / 256), dim3(256), 0, stream>>>(x, cand);
  if (ws_size >= need) {
    const size_t tau_lds = (size_t)TNTS * 64 * 17 * sizeof(float);  // 69,632 B
    tau_stage_kernel<<<dim3(512), dim3(1024), tau_lds, stream>>>(cand, tauArr);
    filter_select_kernel<<<dim3(512), dim3(512), 0, stream>>>(cand, tauArr, out);
  } else {
    knn_eigen_fallback<<<dim3(NPTS / QPB), dim3(512), 0, stream>>>(cand, out);
  }
}

// Round 11
// 252.428 us; speedup vs baseline: 1.0341x; 1.0341x over previous
//
#include <hip/hip_runtime.h>
#include <math.h>

#define NB 4
#define NP 8192
#define KK 16
#define QPB 64
#define NPTS (NB * NP)

// ---- staged-filter geometry (round 11 = R9 + fast eigen tail) ----
#define TSAMP 2048            // tau sample = candidates [0,2048)
#define TCH 256               // tau subchunk per wave
#define NTS 8                 // tau: 8 waves per query-group
#define BCH 1024              // filter chunk size   (R5/R7/R8 proven: zero overflow)
#define NBCH 8                // 8 chunks cover [0,8192)
#define CAP 30                // per-(query,chunk) capacity (proven geometry)
#define SROW 34               // u16 per (chunk,query) LDS row: [0]=cnt,[1..30]=idx (+pad)
#define SCH (64 * SROW + 2)   // LDS chunk stride in u16
#define RECW 248              // u16 per query record (496 B)
#define RECCAP 240            // max survivors stored per query
// record layout: [0]=total cnt (0xFFFF = overflow flag), [1..7] pad,
//                [8..8+239] survivor indices, ascending global index.
// Fail-safe: tau = exact ref 16th-smallest of first 2048 => >=16 survivors,
// top-16 subset of survivors. Flagged record => exact full-scan. Selection
// stream order identical to R8/R9 (absmax 0.0 proven).

// comparator macros (exact: min/max introduce no rounding)
#define CSWAP_DESC(a, b) { float _lo = fminf(a, b); float _hi = fmaxf(a, b); a = _hi; b = _lo; }
#define CSWAP_ASC(a, b)  { float _lo = fminf(a, b); float _hi = fmaxf(a, b); a = _lo; b = _hi; }

// reference-rounded |p|^2 : (xx+yy)+zz
__device__ __forceinline__ float ref_sq(float x, float y, float z) {
  return __fadd_rn(__fadd_rn(__fmul_rn(x, x), __fmul_rn(y, y)), __fmul_rn(z, z));
}

// reference-rounded d2 = (sqq + sqc) - 2*dot, dot = (xx+yy)+zz
__device__ __forceinline__ float ref_d2q(float qx, float qy, float qz, float sqq,
                                         float4 c) {
  float dot = __fadd_rn(__fadd_rn(__fmul_rn(qx, c.x), __fmul_rn(qy, c.y)),
                        __fmul_rn(qz, c.z));
  float s = __fadd_rn(sqq, c.w);
  return __fmaf_rn(-2.0f, dot, s);
}

// ---- eigen-ratio from covariance/K entries: f64 algebra, f32-trig seeds +
// guarded double-Newton refinement of y^3 - 3y - 2r = 0 (B's char poly:
// tr B = 0, tr B^2 = 6). Replaces libm acos/cos(double) (software f64 trig,
// tens of kcycles/thread, un-hideable at 2 waves/CU). Non-degenerate roots
// converge quadratically to ~1e-15 (accuracy-equivalent to double trig);
// degenerate (r ~ -1 <=> lambda0 ~ lambda1, ratio ~ 1) keeps the ~1e-4 seed
// -- ratio error <= ~1e-3, far under the 0.028 absmax margin.
__device__ __forceinline__ double eigen_ratio_tail(
    float cxx, float cyy, float czz, float cxy, float cxz, float cyz,
    float k1) {
  double a   = (double)__fmul_rn(cxx, k1), b = (double)__fmul_rn(cyy, k1);
  double c2  = (double)__fmul_rn(czz, k1);
  double dxy = (double)__fmul_rn(cxy, k1), exz = (double)__fmul_rn(cxz, k1);
  double fyz = (double)__fmul_rn(cyz, k1);
  double qm = (a + b + c2) / 3.0;
  double p1 = dxy * dxy + exz * exz + fyz * fyz;
  double aa = a - qm, bb = b - qm, cc = c2 - qm;
  double p2 = aa * aa + bb * bb + cc * cc + 2.0 * p1;
  if (p2 <= 0.0) return 1.0;
  double p  = sqrt(p2 / 6.0);
  double ip = 1.0 / p;
  double b00 = aa * ip, b11 = bb * ip, b22 = cc * ip;
  double b01 = dxy * ip, b02 = exz * ip, b12 = fyz * ip;
  double detB = b00 * (b11 * b22 - b12 * b12)
              - b01 * (b01 * b22 - b12 * b02)
              + b02 * (b01 * b12 - b11 * b02);
  double r = 0.5 * detB;
  r = fmin(1.0, fmax(-1.0, r));
  const double dcl = 2.0 * r;                 // cubic constant
  // f32 hardware-trig seeds
  float phif = acosf((float)r) * (1.0f / 3.0f);
  double y0 = 2.0 * (double)cosf(phif);                     // largest root
  double y2 = 2.0 * (double)cosf(phif + 2.0943951f);        // smallest root
  // guarded Newton (3 iters, double)
#pragma unroll
  for (int it = 0; it < 3; ++it) {
    double g0 = 3.0 * (y0 * y0 - 1.0);
    if (fabs(g0) > 1e-4) y0 -= (y0 * y0 * y0 - 3.0 * y0 - dcl) / g0;
    double g2 = 3.0 * (y2 * y2 - 1.0);
    if (fabs(g2) > 1e-4) y2 -= (y2 * y2 * y2 - 3.0 * y2 - dcl) / g2;
  }
  double e0 = qm + p * y0;                    // largest
  double e2v = qm + p * y2;                   // smallest
  double e1 = 3.0 * qm - e0 - e2v;            // middle
  return e0 / e1;
}

// batched top-16 update: 8 new distances d[0..7] vs sorted-asc bd[0..15]
__device__ __forceinline__ void topk_update(float bd[KK], float d[8]) {
  CSWAP_DESC(d[0], d[1]) CSWAP_DESC(d[2], d[3]) CSWAP_DESC(d[4], d[5]) CSWAP_DESC(d[6], d[7])
  CSWAP_DESC(d[0], d[2]) CSWAP_DESC(d[1], d[3]) CSWAP_DESC(d[4], d[6]) CSWAP_DESC(d[5], d[7])
  CSWAP_DESC(d[1], d[2]) CSWAP_DESC(d[5], d[6])
  CSWAP_DESC(d[0], d[4]) CSWAP_DESC(d[1], d[5]) CSWAP_DESC(d[2], d[6]) CSWAP_DESC(d[3], d[7])
  CSWAP_DESC(d[2], d[4]) CSWAP_DESC(d[3], d[5])
  CSWAP_DESC(d[1], d[2]) CSWAP_DESC(d[3], d[4]) CSWAP_DESC(d[5], d[6])
#pragma unroll
  for (int i = 0; i < 8; ++i) bd[8 + i] = fminf(bd[8 + i], d[i]);
#pragma unroll
  for (int i = 0; i < 8; ++i)  CSWAP_ASC(bd[i], bd[i + 8])
#pragma unroll
  for (int i = 0; i < 4; ++i)  CSWAP_ASC(bd[i], bd[i + 4])
#pragma unroll
  for (int i = 8; i < 12; ++i) CSWAP_ASC(bd[i], bd[i + 4])
#pragma unroll
  for (int g = 0; g < 4; ++g) {
    CSWAP_ASC(bd[4 * g + 0], bd[4 * g + 2]) CSWAP_ASC(bd[4 * g + 1], bd[4 * g + 3])
    CSWAP_ASC(bd[4 * g + 0], bd[4 * g + 1]) CSWAP_ASC(bd[4 * g + 2], bd[4 * g + 3])
  }
}

__global__ void prep_kernel(const float* __restrict__ x,
                            float4* __restrict__ cand) {
  int i = blockIdx.x * 256 + threadIdx.x;
  if (i < NPTS) {
    float px = x[3 * i + 0], py = x[3 * i + 1], pz = x[3 * i + 2];
    cand[i] = make_float4(px, py, pz, ref_sq(px, py, pz));
  }
}

// ---------------- kA: tau = 16th-smallest ref-dist over [0,2048) ------------
// VERBATIM R9: sample staged into LDS once per block, scan from LDS, merge
// region overlays sample after barrier. tau errors harmless (fail-safe).
__global__ __launch_bounds__(512) void tau_stage_kernel(
    const float4* __restrict__ cand, float* __restrict__ tauArr) {
  __shared__ __align__(16) char smem[NTS * 64 * 17 * 4];   // 34,816 B
  float4* samp = (float4*)smem;                            // [2048] phases 1-2
  float (*s_t)[64][17] = (float (*)[64][17])smem;          // [8][64][17] 3-4
  const int tid   = threadIdx.x;
  const int lane  = tid & 63;
  const int w     = __builtin_amdgcn_readfirstlane(tid >> 6);
  const int group = blockIdx.x;              // 0..511
  const int batch = group >> 7;
  const int qbase = (group & 127) * QPB;
  const float4* __restrict__ Cb = cand + (size_t)batch * NP;

  const float4 q = Cb[qbase + lane];
  const float qx = q.x, qy = q.y, qz = q.z, sqq = q.w;

#pragma unroll
  for (int r = 0; r < TSAMP / 512; ++r)
    samp[r * 512 + tid] = Cb[r * 512 + tid];
  __syncthreads();

  float bd[KK];
#pragma unroll
  for (int t = 0; t < KK; ++t) bd[t] = 3.4e38f;

  const int j0 = w * TCH;
  for (int jj = 0; jj < TCH; jj += 8) {
    const float4* xp = samp + (j0 + jj);     // uniform LDS addr: broadcast
    float4 c[8];
#pragma unroll
    for (int u = 0; u < 8; ++u) c[u] = xp[u];
    float d[8];
#pragma unroll
    for (int u = 0; u < 8; ++u) d[u] = ref_d2q(qx, qy, qz, sqq, c[u]);
    topk_update(bd, d);
  }
  __syncthreads();

#pragma unroll
  for (int t = 0; t < KK; ++t) s_t[w][lane][t] = bd[t];
  __syncthreads();

  if (w == 0) {
    float md[KK];
#pragma unroll
    for (int t = 0; t < KK; ++t) md[t] = s_t[0][lane][t];
#pragma unroll
    for (int s2 = 1; s2 < NTS; ++s2) {
      float d[KK];
#pragma unroll
      for (int t = 0; t < KK; ++t) d[t] = s_t[s2][lane][t];
      topk_update(md, &d[0]);
      topk_update(md, &d[8]);
    }
    tauArr[batch * NP + qbase + lane] = md[KK - 1];
  }
}

// ---------------- kB: threshold filter -> LDS -> compact global record ------
// VERBATIM R8/R9 (measured 87us anchor).
__global__ __launch_bounds__(512) void filter_kernel(
    const float4* __restrict__ cand, const float* __restrict__ tauArr,
    unsigned short* __restrict__ rec) {
  __shared__ unsigned short s_idx[NBCH * SCH];   // 34,848 B
  const int tid   = threadIdx.x;
  const int lane  = tid & 63;
  const int w     = __builtin_amdgcn_readfirstlane(tid >> 6);
  const int group = blockIdx.x;              // 0..511
  const int batch = group >> 7;
  const int qbase = (group & 127) * QPB;
  const int j0    = w * BCH;
  const float4* __restrict__ Cb = cand + (size_t)batch * NP;

  const int qg = batch * NP + qbase + lane;
  const float tau = tauArr[qg];
  const float4 q = Cb[qbase + lane];
  const float qx = q.x, qy = q.y, qz = q.z, sqq = q.w;

  unsigned short* Srow = &s_idx[w * SCH + lane * SROW];
  int cnt = 0;
  for (int jj = 0; jj < BCH; jj += 16) {
    const float4* xp = Cb + (j0 + jj);       // wave-uniform address
    float4 c[16];
#pragma unroll
    for (int u = 0; u < 16; ++u) c[u] = xp[u];   // 16 loads in flight
#pragma unroll
    for (int u = 0; u < 16; ++u) {
      float d = ref_d2q(qx, qy, qz, sqq, c[u]);
      if (d <= tau) {
        if (cnt < CAP) Srow[1 + cnt] = (unsigned short)(j0 + jj + u);
        ++cnt;                               // count ALL survivors
      }
    }
  }
  Srow[0] = (unsigned short)cnt;
  __syncthreads();

  // compaction: 8 threads per query (ql = tid>>3, p = tid&7 = source chunk)
  const int ql = tid >> 3;
  const int p  = tid & 7;
  int off = 0, myc = 0, total = 0, mx = 0;
#pragma unroll
  for (int c = 0; c < NBCH; ++c) {
    const int cc  = (int)s_idx[c * SCH + ql * SROW];
    const int ccw = cc < CAP ? cc : CAP;
    if (c < p) off += ccw;
    if (c == p) myc = ccw;
    total += cc;
    mx = cc > mx ? cc : mx;
  }
  const int qg2 = batch * NP + qbase + ql;
  unsigned short* R = rec + (size_t)qg2 * RECW;
  if (p == 0)
    R[0] = (unsigned short)((mx > CAP || total > RECCAP) ? 0xFFFFu
                                                         : (unsigned)total);
  const unsigned short* Ssrc = &s_idx[p * SCH + ql * SROW + 1];
  for (int e = 0; e < myc; ++e) {
    const int dst = off + e;
    if (dst < RECCAP) R[8 + dst] = Ssrc[e];
  }
}

// ---------------- kC: single-pass exact top-16 + covariance + eigen --------
// R9 structure verbatim (16-wide super-batches, pts cache); ONLY the eigen
// tail is swapped to eigen_ratio_tail (f32-trig seed + double Newton).
__global__ __launch_bounds__(64) void select_eigen_kernel(
    const float4* __restrict__ cand, const unsigned short* __restrict__ rec,
    float* __restrict__ out) {
  const int tid = threadIdx.x;
  const int g = blockIdx.x * 64 + tid;       // global query id
  const int batch = g >> 13;                 // / NP
  const float4* __restrict__ Cb = cand + (size_t)batch * NP;
  const unsigned short* R = rec + (size_t)g * RECW;

  const float4 qq = Cb[g & (NP - 1)];
  const float q2x = qq.x, q2y = qq.y, q2z = qq.z, sq2 = qq.w;

  const int cntw = (int)R[0];
  bool fs = (cntw == 0xFFFF) || (cntw < KK);
  const int cnt = fs ? 0 : cntw;

  float md[KK]; int mjr[KK];
#pragma unroll
  for (int t = 0; t < KK; ++t) { md[t] = 3.4e38f; mjr[t] = 0; }

  if (!fs) {
    const unsigned short* L = R + 8;         // 16B-aligned survivor stream
    for (int e = 0; e < cnt; e += 16) {
      const int4 raw0 = *(const int4*)(L + e);      // dwordx4: 8 indices
      const int4 raw1 = *(const int4*)(L + e + 8);  // dwordx4: 8 more
      int jv[16];
      jv[0]  = raw0.x & 0xFFFF;  jv[1]  = (raw0.x >> 16) & 0xFFFF;
      jv[2]  = raw0.y & 0xFFFF;  jv[3]  = (raw0.y >> 16) & 0xFFFF;
      jv[4]  = raw0.z & 0xFFFF;  jv[5]  = (raw0.z >> 16) & 0xFFFF;
      jv[6]  = raw0.w & 0xFFFF;  jv[7]  = (raw0.w >> 16) & 0xFFFF;
      jv[8]  = raw1.x & 0xFFFF;  jv[9]  = (raw1.x >> 16) & 0xFFFF;
      jv[10] = raw1.y & 0xFFFF;  jv[11] = (raw1.y >> 16) & 0xFFFF;
      jv[12] = raw1.z & 0xFFFF;  jv[13] = (raw1.z >> 16) & 0xFFFF;
      jv[14] = raw1.w & 0xFFFF;  jv[15] = (raw1.w >> 16) & 0xFFFF;
      float dv[16];
#pragma unroll
      for (int u = 0; u < 16; ++u) {
        const bool ok = (e + u) < cnt;
        const int j = ok ? jv[u] : 0;        // mask BEFORE gather
        jv[u] = j;
        const float dd = ref_d2q(q2x, q2y, q2z, sq2, Cb[j]);  // 16 in flight
        dv[u] = ok ? dd : 3.4e38f;           // +inf pad: chain no-op
      }
#pragma unroll
      for (int u = 0; u < 16; ++u) {
        const float d = dv[u];
        const int j = jv[u];
        if (d < md[KK - 1]) {
          bool c0 = d < md[0];
#pragma unroll
          for (int t = KK - 1; t >= 1; --t) {
            bool cl = d < md[t];
            bool cp = d < md[t - 1];
            float nv = fmaxf(md[t - 1], fminf(md[t], d));
            mjr[t] = cl ? (cp ? mjr[t - 1] : j) : mjr[t];
            md[t] = nv;
          }
          mjr[0] = c0 ? j : mjr[0];
          md[0] = fminf(md[0], d);
        }
      }
    }
  } else {
    // exact full-scan insertion with index tracking (verbatim-proven)
    for (int j = 0; j < NP; ++j) {
      float d = ref_d2q(q2x, q2y, q2z, sq2, Cb[j]);
      if (d < md[KK - 1]) {
        bool c0 = d < md[0];
#pragma unroll
        for (int t = KK - 1; t >= 1; --t) {
          bool cl = d < md[t];
          bool cp = d < md[t - 1];
          float nv = fmaxf(md[t - 1], fminf(md[t], d));
          mjr[t] = cl ? (cp ? mjr[t - 1] : j) : mjr[t];
          md[t] = nv;
        }
        mjr[0] = c0 ? j : mjr[0];
        md[0] = fminf(md[0], d);
      }
    }
  }

  // cache the 16 selected points once (bitwise-identical values)
  float4 pts[KK];
#pragma unroll
  for (int s = 0; s < KK; ++s) pts[s] = Cb[mjr[s]];

  // ---- covariance (verbatim) + fast eigen tail
  float sx = 0.f, sy = 0.f, sz = 0.f;
#pragma unroll
  for (int s = 0; s < KK; ++s) {
    sx = __fadd_rn(sx, pts[s].x);
    sy = __fadd_rn(sy, pts[s].y);
    sz = __fadd_rn(sz, pts[s].z);
  }
  const float k1 = 1.0f / KK;   // exact power of two
  const float mx = sx * k1, my = sy * k1, mz = sz * k1;

  float cxx = 0.f, cxy = 0.f, cxz = 0.f, cyy = 0.f, cyz = 0.f, czz = 0.f;
#pragma unroll
  for (int s = 0; s < KK; ++s) {
    float dx = __fsub_rn(pts[s].x, mx);
    float dy = __fsub_rn(pts[s].y, my);
    float dz = __fsub_rn(pts[s].z, mz);
    cxx = __fadd_rn(cxx, __fmul_rn(dx, dx));
    cxy = __fadd_rn(cxy, __fmul_rn(dx, dy));
    cxz = __fadd_rn(cxz, __fmul_rn(dx, dz));
    cyy = __fadd_rn(cyy, __fmul_rn(dy, dy));
    cyz = __fadd_rn(cyz, __fmul_rn(dy, dz));
    czz = __fadd_rn(czz, __fmul_rn(dz, dz));
  }

  out[g] = (float)eigen_ratio_tail(cxx, cyy, czz, cxy, cxz, cyz, k1);
}

// ---------------- fallback: verbatim single kernel (proven pass) ------------
__global__ __launch_bounds__(512, 4) void knn_eigen_fallback(
    const float4* __restrict__ cand, float* __restrict__ out) {
  __shared__ unsigned short s_j[8][QPB][18];

  const int tid   = threadIdx.x;
  const int lane  = tid & 63;
  const int w     = __builtin_amdgcn_readfirstlane(tid >> 6);
  const int batch = blockIdx.x >> 7;
  const int qbase = (blockIdx.x & 127) * QPB;
  const int FCH   = NP / 8;   // 1024

  const float4* __restrict__ Cb = cand + (size_t)batch * NP;

  const float4 q = Cb[qbase + lane];
  const float qx = q.x, qy = q.y, qz = q.z, sqq = q.w;

  float bd[KK];
#pragma unroll
  for (int t = 0; t < KK; ++t) bd[t] = 3.4e38f;

  const int j0 = w * FCH;
  for (int jj = 0; jj < FCH; jj += 8) {
    const float4* xp = Cb + (j0 + jj);
    float4 c[8];
#pragma unroll
    for (int u = 0; u < 8; ++u) c[u] = xp[u];
    float d[8];
#pragma unroll
    for (int u = 0; u < 8; ++u) d[u] = ref_d2q(qx, qy, qz, sqq, c[u]);
    topk_update(bd, d);
  }

  const float T = bd[KK - 1];
  int cnt = 0;
  for (int jj = 0; jj < FCH; jj += 8) {
    const float4* xp = Cb + (j0 + jj);
    float4 c[8];
#pragma unroll
    for (int u = 0; u < 8; ++u) c[u] = xp[u];
#pragma unroll
    for (int u = 0; u < 8; ++u) {
      float d = ref_d2q(qx, qy, qz, sqq, c[u]);
      if (d <= T && cnt < KK) {
        s_j[w][lane][cnt] = (unsigned short)(j0 + jj + u);
        cnt++;
      }
    }
  }
  __syncthreads();

  if (tid < QPB) {
    const float4 qq = Cb[qbase + tid];
    const float q2x = qq.x, q2y = qq.y, q2z = qq.z, sq2 = qq.w;
    float md[KK]; int mj[KK];
#pragma unroll
    for (int t = 0; t < KK; ++t) { md[t] = 3.4e38f; mj[t] = 0; }
    for (int cch = 0; cch < 8; ++cch) {
      const unsigned int* rowp = (const unsigned int*)&s_j[cch][tid][0];
#pragma unroll
      for (int sp = 0; sp < KK / 2; ++sp) {
        unsigned int pk = rowp[sp];
#pragma unroll
        for (int half = 0; half < 2; ++half) {
          int j = (half == 0) ? (int)(pk & 0xFFFFu) : (int)(pk >> 16);
          float d = ref_d2q(q2x, q2y, q2z, sq2, Cb[j]);
          if (d < md[KK - 1]) {
            bool c0 = d < md[0];
#pragma unroll
            for (int t = KK - 1; t >= 1; --t) {
              bool cl = d < md[t];
              bool cp = d < md[t - 1];
              float nv = fmaxf(md[t - 1], fminf(md[t], d));
              mj[t] = cl ? (cp ? mj[t - 1] : j) : mj[t];
              md[t] = nv;
            }
            mj[0] = c0 ? j : mj[0];
            md[0] = fminf(md[0], d);
          }
        }
      }
    }
    float sx = 0.f, sy = 0.f, sz = 0.f;
#pragma unroll
    for (int s = 0; s < KK; ++s) {
      float4 pp = Cb[mj[s]];
      sx = __fadd_rn(sx, pp.x);
      sy = __fadd_rn(sy, pp.y);
      sz = __fadd_rn(sz, pp.z);
    }
    const float k1 = 1.0f / KK;
    const float mx = sx * k1, my = sy * k1, mz = sz * k1;
    float cxx = 0.f, cxy = 0.f, cxz = 0.f, cyy = 0.f, cyz = 0.f, czz = 0.f;
#pragma unroll
    for (int s = 0; s < KK; ++s) {
      float4 pp = Cb[mj[s]];
      float dx = __fsub_rn(pp.x, mx);
      float dy = __fsub_rn(pp.y, my);
      float dz = __fsub_rn(pp.z, mz);
      cxx = __fadd_rn(cxx, __fmul_rn(dx, dx));
      cxy = __fadd_rn(cxy, __fmul_rn(dx, dy));
      cxz = __fadd_rn(cxz, __fmul_rn(dx, dz));
      cyy = __fadd_rn(cyy, __fmul_rn(dy, dy));
      cyz = __fadd_rn(cyz, __fmul_rn(dy, dz));
      czz = __fadd_rn(czz, __fmul_rn(dz, dz));
    }
    out[(size_t)batch * NP + qbase + tid] =
        (float)eigen_ratio_tail(cxx, cyy, czz, cxy, cxz, cyz, k1);
  }
}

extern "C" void kernel_launch(void* const* d_in, const int* in_sizes, int n_in,
                              void* d_out, int out_size, void* d_ws, size_t ws_size,
                              hipStream_t stream) {
  const float* x = (const float*)d_in[0];
  float* out = (float*)d_out;
  float4* cand = (float4*)d_ws;                                   // 512 KB
  float* tauArr = (float*)((char*)d_ws + (size_t)NPTS * sizeof(float4)); // 128 KB
  unsigned short* rec =
      (unsigned short*)((char*)d_ws + (size_t)NPTS * sizeof(float4) +
                        (size_t)NPTS * sizeof(float));            // 15.5 MB
  const size_t need = (size_t)NPTS * sizeof(float4) +
                      (size_t)NPTS * sizeof(float) +
                      (size_t)NPTS * RECW * sizeof(unsigned short);
  // need = 16,908,288 B == proven budget

  prep_kernel<<<dim3(NPTS / 256), dim3(256), 0, stream>>>(x, cand);
  if (ws_size >= need) {
    tau_stage_kernel<<<dim3(512), dim3(512), 0, stream>>>(cand, tauArr);
    filter_kernel<<<dim3(512), dim3(512), 0, stream>>>(cand, tauArr, rec);
    select_eigen_kernel<<<dim3(NPTS / 64), dim3(64), 0, stream>>>(cand, rec, out);
  } else {
    knn_eigen_fallback<<<dim3(NPTS / QPB), dim3(512), 0, stream>>>(cand, out);
  }
}

// Round 12
// 200.656 us; speedup vs baseline: 1.3009x; 1.2580x over previous
//
#include <hip/hip_runtime.h>
#include <math.h>

#define NB 4
#define NP 8192
#define KK 16
#define QPB 64
#define NPTS (NB * NP)

// ---- geometry (round 12) ----
#define TSAMP 2048            // tau sample = candidates [0,2048)
#define TCH 256               // tau subchunk per wave
#define NTS 8                 // tau: 8 waves per query-group
#define BCH 1024              // filter chunk size (proven zero-overflow)
#define NBCH 8                // 8 chunks cover [0,8192)
#define CAP 30                // per-(query,chunk) capacity (proven geometry)
#define SROW 34               // u16 per (chunk,query) LDS row: [0]=unused,[1..30]=idx
#define SCH (64 * SROW + 2)   // LDS chunk stride in u16
#define PADKEY 0xFFFFFFFFFFFFFFFFull
// LDS (dynamic, 66,560B): [0,65536) = union{ s_idx u16 rows (filter phase),
// keys u64[64][8][16] (select phase, overlays after barrier) };
// [65536,66560) = s_cnt u16[8][64].
// Selection semantics: key = (orderable(d) << 32) | j gives the EXACT total
// order (d asc, j asc) that the proven insertion chain implements (ties by
// stream position; stream order == ascending global index since chunks
// partition [0,8192) in order). Per-chunk top-16 by key -> 8-way merge ->
// global top-16 in identical order -> bitwise-identical covariance sums.
// Fail-safe: chunk cnt > CAP or total < 16 => proven exact full-scan.

// comparator macros (exact: min/max introduce no rounding)
#define CSWAP_DESC(a, b) { float _lo = fminf(a, b); float _hi = fmaxf(a, b); a = _hi; b = _lo; }
#define CSWAP_ASC(a, b)  { float _lo = fminf(a, b); float _hi = fmaxf(a, b); a = _lo; b = _hi; }

__device__ __forceinline__ float ref_sq(float x, float y, float z) {
  return __fadd_rn(__fadd_rn(__fmul_rn(x, x), __fmul_rn(y, y)), __fmul_rn(z, z));
}

__device__ __forceinline__ float ref_d2q(float qx, float qy, float qz, float sqq,
                                         float4 c) {
  float dot = __fadd_rn(__fadd_rn(__fmul_rn(qx, c.x), __fmul_rn(qy, c.y)),
                        __fmul_rn(qz, c.z));
  float s = __fadd_rn(sqq, c.w);
  return __fmaf_rn(-2.0f, dot, s);
}

// order-preserving float->u32 (total order == float compare for non-NaN)
__device__ __forceinline__ unsigned int ord_f32(float d) {
  unsigned int b = __float_as_uint(d);
  return b ^ ((b >> 31) ? 0xFFFFFFFFu : 0x80000000u);
}

// ---- eigen-ratio tail (R11-proven: absmax 0.0 measured) ----
__device__ __forceinline__ double eigen_ratio_tail(
    float cxx, float cyy, float czz, float cxy, float cxz, float cyz,
    float k1) {
  double a   = (double)__fmul_rn(cxx, k1), b = (double)__fmul_rn(cyy, k1);
  double c2  = (double)__fmul_rn(czz, k1);
  double dxy = (double)__fmul_rn(cxy, k1), exz = (double)__fmul_rn(cxz, k1);
  double fyz = (double)__fmul_rn(cyz, k1);
  double qm = (a + b + c2) / 3.0;
  double p1 = dxy * dxy + exz * exz + fyz * fyz;
  double aa = a - qm, bb = b - qm, cc = c2 - qm;
  double p2 = aa * aa + bb * bb + cc * cc + 2.0 * p1;
  if (p2 <= 0.0) return 1.0;
  double p  = sqrt(p2 / 6.0);
  double ip = 1.0 / p;
  double b00 = aa * ip, b11 = bb * ip, b22 = cc * ip;
  double b01 = dxy * ip, b02 = exz * ip, b12 = fyz * ip;
  double detB = b00 * (b11 * b22 - b12 * b12)
              - b01 * (b01 * b22 - b12 * b02)
              + b02 * (b01 * b12 - b11 * b02);
  double r = 0.5 * detB;
  r = fmin(1.0, fmax(-1.0, r));
  const double dcl = 2.0 * r;
  float phif = acosf((float)r) * (1.0f / 3.0f);
  double y0 = 2.0 * (double)cosf(phif);
  double y2 = 2.0 * (double)cosf(phif + 2.0943951f);
#pragma unroll
  for (int it = 0; it < 3; ++it) {
    double g0 = 3.0 * (y0 * y0 - 1.0);
    if (fabs(g0) > 1e-4) y0 -= (y0 * y0 * y0 - 3.0 * y0 - dcl) / g0;
    double g2 = 3.0 * (y2 * y2 - 1.0);
    if (fabs(g2) > 1e-4) y2 -= (y2 * y2 * y2 - 3.0 * y2 - dcl) / g2;
  }
  double e0 = qm + p * y0;
  double e2v = qm + p * y2;
  double e1 = 3.0 * qm - e0 - e2v;
  return e0 / e1;
}

// batched top-16 update: 8 new distances d[0..7] vs sorted-asc bd[0..15]
__device__ __forceinline__ void topk_update(float bd[KK], float d[8]) {
  CSWAP_DESC(d[0], d[1]) CSWAP_DESC(d[2], d[3]) CSWAP_DESC(d[4], d[5]) CSWAP_DESC(d[6], d[7])
  CSWAP_DESC(d[0], d[2]) CSWAP_DESC(d[1], d[3]) CSWAP_DESC(d[4], d[6]) CSWAP_DESC(d[5], d[7])
  CSWAP_DESC(d[1], d[2]) CSWAP_DESC(d[5], d[6])
  CSWAP_DESC(d[0], d[4]) CSWAP_DESC(d[1], d[5]) CSWAP_DESC(d[2], d[6]) CSWAP_DESC(d[3], d[7])
  CSWAP_DESC(d[2], d[4]) CSWAP_DESC(d[3], d[5])
  CSWAP_DESC(d[1], d[2]) CSWAP_DESC(d[3], d[4]) CSWAP_DESC(d[5], d[6])
#pragma unroll
  for (int i = 0; i < 8; ++i) bd[8 + i] = fminf(bd[8 + i], d[i]);
#pragma unroll
  for (int i = 0; i < 8; ++i)  CSWAP_ASC(bd[i], bd[i + 8])
#pragma unroll
  for (int i = 0; i < 4; ++i)  CSWAP_ASC(bd[i], bd[i + 4])
#pragma unroll
  for (int i = 8; i < 12; ++i) CSWAP_ASC(bd[i], bd[i + 4])
#pragma unroll
  for (int g = 0; g < 4; ++g) {
    CSWAP_ASC(bd[4 * g + 0], bd[4 * g + 2]) CSWAP_ASC(bd[4 * g + 1], bd[4 * g + 3])
    CSWAP_ASC(bd[4 * g + 0], bd[4 * g + 1]) CSWAP_ASC(bd[4 * g + 2], bd[4 * g + 3])
  }
}

__global__ void prep_kernel(const float* __restrict__ x,
                            float4* __restrict__ cand) {
  int i = blockIdx.x * 256 + threadIdx.x;
  if (i < NPTS) {
    float px = x[3 * i + 0], py = x[3 * i + 1], pz = x[3 * i + 2];
    cand[i] = make_float4(px, py, pz, ref_sq(px, py, pz));
  }
}

// ---------------- kA: tau (VERBATIM R11/R9 structure) -----------------------
__global__ __launch_bounds__(512) void tau_stage_kernel(
    const float4* __restrict__ cand, float* __restrict__ tauArr) {
  __shared__ __align__(16) char smem[NTS * 64 * 17 * 4];   // 34,816 B
  float4* samp = (float4*)smem;
  float (*s_t)[64][17] = (float (*)[64][17])smem;
  const int tid   = threadIdx.x;
  const int lane  = tid & 63;
  const int w     = __builtin_amdgcn_readfirstlane(tid >> 6);
  const int group = blockIdx.x;
  const int batch = group >> 7;
  const int qbase = (group & 127) * QPB;
  const float4* __restrict__ Cb = cand + (size_t)batch * NP;

  const float4 q = Cb[qbase + lane];
  const float qx = q.x, qy = q.y, qz = q.z, sqq = q.w;

#pragma unroll
  for (int r = 0; r < TSAMP / 512; ++r)
    samp[r * 512 + tid] = Cb[r * 512 + tid];
  __syncthreads();

  float bd[KK];
#pragma unroll
  for (int t = 0; t < KK; ++t) bd[t] = 3.4e38f;

  const int j0 = w * TCH;
  for (int jj = 0; jj < TCH; jj += 8) {
    const float4* xp = samp + (j0 + jj);
    float4 c[8];
#pragma unroll
    for (int u = 0; u < 8; ++u) c[u] = xp[u];
    float d[8];
#pragma unroll
    for (int u = 0; u < 8; ++u) d[u] = ref_d2q(qx, qy, qz, sqq, c[u]);
    topk_update(bd, d);
  }
  __syncthreads();

#pragma unroll
  for (int t = 0; t < KK; ++t) s_t[w][lane][t] = bd[t];
  __syncthreads();

  if (w == 0) {
    float md[KK];
#pragma unroll
    for (int t = 0; t < KK; ++t) md[t] = s_t[0][lane][t];
#pragma unroll
    for (int s2 = 1; s2 < NTS; ++s2) {
      float d[KK];
#pragma unroll
      for (int t = 0; t < KK; ++t) d[t] = s_t[s2][lane][t];
      topk_update(md, &d[0]);
      topk_update(md, &d[8]);
    }
    tauArr[batch * NP + qbase + lane] = md[KK - 1];
  }
}

// ---------------- kB: fused filter + parallel select + eigen ----------------
__global__ __launch_bounds__(512) void filter_select_kernel(
    const float4* __restrict__ cand, const float* __restrict__ tauArr,
    float* __restrict__ out) {
  extern __shared__ __align__(16) char smem[];
  unsigned short* s_idx = (unsigned short*)smem;                 // phase 1
  unsigned long long* keys = (unsigned long long*)smem;          // phase 2+
  unsigned short* s_cnt = (unsigned short*)(smem + 65536);       // [8][64]

  const int tid   = threadIdx.x;
  const int lane  = tid & 63;
  const int w     = __builtin_amdgcn_readfirstlane(tid >> 6);
  const int group = blockIdx.x;              // 0..511
  const int batch = group >> 7;
  const int qbase = (group & 127) * QPB;
  const float4* __restrict__ Cb = cand + (size_t)batch * NP;

  // ---- phase 1: filter (R8-proven body; cnt to s_cnt) ----
  {
    const int j0 = w * BCH;
    const float tau = tauArr[batch * NP + qbase + lane];
    const float4 q = Cb[qbase + lane];
    const float qx = q.x, qy = q.y, qz = q.z, sqq = q.w;

    unsigned short* Srow = &s_idx[w * SCH + lane * SROW];
    int cnt = 0;
    for (int jj = 0; jj < BCH; jj += 16) {
      const float4* xp = Cb + (j0 + jj);     // wave-uniform address
      float4 c[16];
#pragma unroll
      for (int u = 0; u < 16; ++u) c[u] = xp[u];   // 16 loads in flight
#pragma unroll
      for (int u = 0; u < 16; ++u) {
        float d = ref_d2q(qx, qy, qz, sqq, c[u]);
        if (d <= tau) {
          if (cnt < CAP) Srow[1 + cnt] = (unsigned short)(j0 + jj + u);
          ++cnt;                             // count ALL survivors
        }
      }
    }
    s_cnt[w * 64 + lane] = (unsigned short)cnt;
  }
  __syncthreads();

  // ---- phase 2: 8 threads/query; thread (q,p) -> chunk p's top-16 keys ----
  const int qlq = tid >> 3;                  // query-in-group 0..63
  const int pch = tid & 7;                   // source chunk 0..7
  unsigned long long slots[KK];
#pragma unroll
  for (int t = 0; t < KK; ++t) slots[t] = PADKEY;
  {
    const float4 qq = Cb[qbase + qlq];
    const float q2x = qq.x, q2y = qq.y, q2z = qq.z, sq2 = qq.w;
    const unsigned short* row = &s_idx[pch * SCH + qlq * SROW + 1];
    int cnl = (int)s_cnt[pch * 64 + qlq];
    if (cnl > CAP) cnl = CAP;                // overflow query goes fs anyway
    for (int e = 0; e < cnl; e += 8) {
      unsigned long long kv[8];
#pragma unroll
      for (int u = 0; u < 8; ++u) {
        const bool ok = (e + u) < cnl;
        const int j = ok ? (int)row[e + u] : 0;
        const float dd = ref_d2q(q2x, q2y, q2z, sq2, Cb[j]);  // 8 in flight
        kv[u] = ok ? ((((unsigned long long)ord_f32(dd)) << 32) |
                      (unsigned int)j)
                   : PADKEY;
      }
#pragma unroll
      for (int u = 0; u < 8; ++u) {
        const unsigned long long k = kv[u];
        if (k < slots[KK - 1]) {
#pragma unroll
          for (int t = KK - 1; t >= 1; --t) {
            unsigned long long lo =
                (slots[t] < k) ? slots[t] : k;           // min
            slots[t] = (slots[t - 1] > lo) ? slots[t - 1] : lo;  // max
          }
          slots[0] = (slots[0] < k) ? slots[0] : k;
        }
      }
    }
  }
  __syncthreads();                           // all s_idx reads complete

  // write keys (overlays s_idx region): keys[(q*8 + p)*16 + t]
#pragma unroll
  for (int t = 0; t < KK; ++t)
    keys[((qlq << 3) + pch) * KK + t] = slots[t];
  __syncthreads();

  // ---- phase 3+4: one thread per query: merge + covariance + eigen ----
  if (tid < QPB) {
    const int ql = tid;
    const int qg = batch * NP + qbase + ql;
    const float4 qq = Cb[qbase + ql];
    const float q2x = qq.x, q2y = qq.y, q2z = qq.z, sq2 = qq.w;

    int total = 0;
    bool fs = false;
#pragma unroll
    for (int p = 0; p < NBCH; ++p) {
      const int c = (int)s_cnt[p * 64 + ql];
      if (c > CAP) fs = true;
      total += c;
    }
    if (total < KK) fs = true;

    int mjr[KK];
    if (!fs) {
      // 8-way tournament merge of sorted key lists; 16 outputs.
      const unsigned long long* kq = keys + (ql << 3) * KK;
      int head[NBCH];
#pragma unroll
      for (int p = 0; p < NBCH; ++p) head[p] = 0;
#pragma unroll
      for (int t = 0; t < KK; ++t) {
        unsigned long long best = PADKEY;
        int bp = 0;
#pragma unroll
        for (int p = 0; p < NBCH; ++p) {
          const unsigned long long k =
              (head[p] < KK) ? kq[p * KK + head[p]] : PADKEY;
          if (k < best) { best = k; bp = p; }
        }
        head[bp]++;
        mjr[t] = (int)(best & 0xFFFFull);    // j (real keys: < 8192)
      }
    } else {
      // exact full-scan insertion with index tracking (verbatim-proven)
      float md[KK];
#pragma unroll
      for (int t = 0; t < KK; ++t) { md[t] = 3.4e38f; mjr[t] = 0; }
      for (int j = 0; j < NP; ++j) {
        float d = ref_d2q(q2x, q2y, q2z, sq2, Cb[j]);
        if (d < md[KK - 1]) {
          bool c0 = d < md[0];
#pragma unroll
          for (int t = KK - 1; t >= 1; --t) {
            bool cl = d < md[t];
            bool cp = d < md[t - 1];
            float nv = fmaxf(md[t - 1], fminf(md[t], d));
            mjr[t] = cl ? (cp ? mjr[t - 1] : j) : mjr[t];
            md[t] = nv;
          }
          mjr[0] = c0 ? j : mjr[0];
          md[0] = fminf(md[0], d);
        }
      }
    }

    // covariance in merged (d,j) order == proven chain order
    float4 pts[KK];
#pragma unroll
    for (int s = 0; s < KK; ++s) pts[s] = Cb[mjr[s]];

    float sx = 0.f, sy = 0.f, sz = 0.f;
#pragma unroll
    for (int s = 0; s < KK; ++s) {
      sx = __fadd_rn(sx, pts[s].x);
      sy = __fadd_rn(sy, pts[s].y);
      sz = __fadd_rn(sz, pts[s].z);
    }
    const float k1 = 1.0f / KK;
    const float mx = sx * k1, my = sy * k1, mz = sz * k1;

    float cxx = 0.f, cxy = 0.f, cxz = 0.f, cyy = 0.f, cyz = 0.f, czz = 0.f;
#pragma unroll
    for (int s = 0; s < KK; ++s) {
      float dx = __fsub_rn(pts[s].x, mx);
      float dy = __fsub_rn(pts[s].y, my);
      float dz = __fsub_rn(pts[s].z, mz);
      cxx = __fadd_rn(cxx, __fmul_rn(dx, dx));
      cxy = __fadd_rn(cxy, __fmul_rn(dx, dy));
      cxz = __fadd_rn(cxz, __fmul_rn(dx, dz));
      cyy = __fadd_rn(cyy, __fmul_rn(dy, dy));
      cyz = __fadd_rn(cyz, __fmul_rn(dy, dz));
      czz = __fadd_rn(czz, __fmul_rn(dz, dz));
    }

    out[qg] = (float)eigen_ratio_tail(cxx, cyy, czz, cxy, cxz, cyz, k1);
  }
}

// ---------------- fallback: verbatim single kernel (proven pass) ------------
__global__ __launch_bounds__(512, 4) void knn_eigen_fallback(
    const float4* __restrict__ cand, float* __restrict__ out) {
  __shared__ unsigned short s_j[8][QPB][18];

  const int tid   = threadIdx.x;
  const int lane  = tid & 63;
  const int w     = __builtin_amdgcn_readfirstlane(tid >> 6);
  const int batch = blockIdx.x >> 7;
  const int qbase = (blockIdx.x & 127) * QPB;
  const int FCH   = NP / 8;   // 1024

  const float4* __restrict__ Cb = cand + (size_t)batch * NP;

  const float4 q = Cb[qbase + lane];
  const float qx = q.x, qy = q.y, qz = q.z, sqq = q.w;

  float bd[KK];
#pragma unroll
  for (int t = 0; t < KK; ++t) bd[t] = 3.4e38f;

  const int j0 = w * FCH;
  for (int jj = 0; jj < FCH; jj += 8) {
    const float4* xp = Cb + (j0 + jj);
    float4 c[8];
#pragma unroll
    for (int u = 0; u < 8; ++u) c[u] = xp[u];
    float d[8];
#pragma unroll
    for (int u = 0; u < 8; ++u) d[u] = ref_d2q(qx, qy, qz, sqq, c[u]);
    topk_update(bd, d);
  }

  const float T = bd[KK - 1];
  int cnt = 0;
  for (int jj = 0; jj < FCH; jj += 8) {
    const float4* xp = Cb + (j0 + jj);
    float4 c[8];
#pragma unroll
    for (int u = 0; u < 8; ++u) c[u] = xp[u];
#pragma unroll
    for (int u = 0; u < 8; ++u) {
      float d = ref_d2q(qx, qy, qz, sqq, c[u]);
      if (d <= T && cnt < KK) {
        s_j[w][lane][cnt] = (unsigned short)(j0 + jj + u);
        cnt++;
      }
    }
  }
  __syncthreads();

  if (tid < QPB) {
    const float4 qq = Cb[qbase + tid];
    const float q2x = qq.x, q2y = qq.y, q2z = qq.z, sq2 = qq.w;
    float md[KK]; int mj[KK];
#pragma unroll
    for (int t = 0; t < KK; ++t) { md[t] = 3.4e38f; mj[t] = 0; }
    for (int cch = 0; cch < 8; ++cch) {
      const unsigned int* rowp = (const unsigned int*)&s_j[cch][tid][0];
#pragma unroll
      for (int sp = 0; sp < KK / 2; ++sp) {
        unsigned int pk = rowp[sp];
#pragma unroll
        for (int half = 0; half < 2; ++half) {
          int j = (half == 0) ? (int)(pk & 0xFFFFu) : (int)(pk >> 16);
          float d = ref_d2q(q2x, q2y, q2z, sq2, Cb[j]);
          if (d < md[KK - 1]) {
            bool c0 = d < md[0];
#pragma unroll
            for (int t = KK - 1; t >= 1; --t) {
              bool cl = d < md[t];
              bool cp = d < md[t - 1];
              float nv = fmaxf(md[t - 1], fminf(md[t], d));
              mj[t] = cl ? (cp ? mj[t - 1] : j) : mj[t];
              md[t] = nv;
            }
            mj[0] = c0 ? j : mj[0];
            md[0] = fminf(md[0], d);
          }
        }
      }
    }
    float sx = 0.f, sy = 0.f, sz = 0.f;
#pragma unroll
    for (int s = 0; s < KK; ++s) {
      float4 pp = Cb[mj[s]];
      sx = __fadd_rn(sx, pp.x);
      sy = __fadd_rn(sy, pp.y);
      sz = __fadd_rn(sz, pp.z);
    }
    const float k1 = 1.0f / KK;
    const float mx = sx * k1, my = sy * k1, mz = sz * k1;
    float cxx = 0.f, cxy = 0.f, cxz = 0.f, cyy = 0.f, cyz = 0.f, czz = 0.f;
#pragma unroll
    for (int s = 0; s < KK; ++s) {
      float4 pp = Cb[mj[s]];
      float dx = __fsub_rn(pp.x, mx);
      float dy = __fsub_rn(pp.y, my);
      float dz = __fsub_rn(pp.z, mz);
      cxx = __fadd_rn(cxx, __fmul_rn(dx, dx));
      cxy = __fadd_rn(cxy, __fmul_rn(dx, dy));
      cxz = __fadd_rn(cxz, __fmul_rn(dx, dz));
      cyy = __fadd_rn(cyy, __fmul_rn(dy, dy));
      cyz = __fadd_rn(cyz, __fmul_rn(dy, dz));
      czz = __fadd_rn(czz, __fmul_rn(dz, dz));
    }
    out[(size_t)batch * NP + qbase + tid] =
        (float)eigen_ratio_tail(cxx, cyy, czz, cxy, cxz, cyz, k1);
  }
}

extern "C" void kernel_launch(void* const* d_in, const int* in_sizes, int n_in,
                              void* d_out, int out_size, void* d_ws, size_t ws_size,
                              hipStream_t stream) {
  const float* x = (const float*)d_in[0];
  float* out = (float*)d_out;
  float4* cand = (float4*)d_ws;                                   // 512 KB
  float* tauArr = (float*)((char*)d_ws + (size_t)NPTS * sizeof(float4)); // 128 KB
  const size_t need = (size_t)NPTS * sizeof(float4) +
                      (size_t)NPTS * sizeof(float);               // 640 KB

  prep_kernel<<<dim3(NPTS / 256), dim3(256), 0, stream>>>(x, cand);
  if (ws_size >= need) {
    tau_stage_kernel<<<dim3(512), dim3(512), 0, stream>>>(cand, tauArr);
    const size_t fs_lds = 65536 + 1024;      // keys/s_idx union + s_cnt
    filter_select_kernel<<<dim3(512), dim3(512), fs_lds, stream>>>(
        cand, tauArr, out);
  } else {
    knn_eigen_fallback<<<dim3(NPTS / QPB), dim3(512), 0, stream>>>(cand, out);
  }
}

// Round 13
// 187.565 us; speedup vs baseline: 1.3917x; 1.0698x over previous
//
#include <hip/hip_runtime.h>
#include <math.h>

#define NB 4
#define NP 8192
#define KK 16
#define QPB 64
#define NPTS (NB * NP)

// ---- geometry (round 13) ----
#define TSAMP 2048            // tau sample = candidates [0,2048)
#define TCH 256               // tau subchunk per wave
#define NTS 8                 // tau: 8 waves per query-group
#define BCH 1024              // filter chunk size (proven zero-overflow)
#define NBCH 8                // 8 chunks cover [0,8192)
#define CAP 30                // per-(query,chunk) capacity (proven geometry)
#define SROW 34               // u16 per (chunk,query) LDS row: [0]=unused,[1..30]=idx
#define SCH (64 * SROW + 2)   // LDS chunk stride in u16
#define KCH 17                // keys: u64 per chunk-list (16 + 1 pad)
#define KQS (NBCH * KCH + 1)  // keys: u64 per query block (137; kills 32-way conflicts)
#define PADKEY 0xFFFFFFFFFFFFFFFFull
#define TAU_MARGIN 2.5e-4f    // >= 2x the |fast_d2-ref_d2| bound (~3.4e-5)
// LDS (dynamic, 71,168B): [0,70144) = union{ s_idx u16 rows (filter phase),
// keys u64[64][137] (select phase, overlays after barrier) };
// [70144,71168) = s_cnt u16[8][64].
//
// Correctness chain (fail-safe, independent of tau's value):
//  S = {j: fast_d(j) <= tau + MARGIN}. If |S| >= 16 selection needs
//  top-16-by-ref subset of S: tau = 16th-smallest FAST-d over sample
//  >= (16th ref of sample) - 3.4e-5 >= d_ref(16) - 3.4e-5, and for j in
//  ref-top-16: fast_d(j) <= ref_d(j)+3.4e-5 <= d_ref(16)+3.4e-5
//  <= tau + 6.8e-5 <= tau + MARGIN  => subset holds. Phase 2 re-ranks S with
//  EXACT ref_d; key=(orderable(d)<<32)|j reproduces the proven chain's total
//  order (d asc, j asc) -> identical top-16, identical order (absmax 0.0
//  measured R12). Chunk cnt > CAP or total < 16 => proven exact full-scan.

// comparator macros (exact: min/max introduce no rounding)
#define CSWAP_DESC(a, b) { float _lo = fminf(a, b); float _hi = fmaxf(a, b); a = _hi; b = _lo; }
#define CSWAP_ASC(a, b)  { float _lo = fminf(a, b); float _hi = fmaxf(a, b); a = _lo; b = _hi; }

__device__ __forceinline__ float ref_sq(float x, float y, float z) {
  return __fadd_rn(__fadd_rn(__fmul_rn(x, x), __fmul_rn(y, y)), __fmul_rn(z, z));
}

__device__ __forceinline__ float ref_d2q(float qx, float qy, float qz, float sqq,
                                         float4 c) {
  float dot = __fadd_rn(__fadd_rn(__fmul_rn(qx, c.x), __fmul_rn(qy, c.y)),
                        __fmul_rn(qz, c.z));
  float s = __fadd_rn(sqq, c.w);
  return __fmaf_rn(-2.0f, dot, s);
}

// fast 5-op distance; |fast - ref| <= ~3.4e-5 on this data range.
__device__ __forceinline__ float fast_d2(float qx, float qy, float qz, float sqq,
                                         float4 c) {
  float dot = __fmaf_rn(qz, c.z, __fmaf_rn(qy, c.y, __fmul_rn(qx, c.x)));
  float s = __fadd_rn(sqq, c.w);
  return __fmaf_rn(-2.0f, dot, s);
}

// order-preserving float->u32 (total order == float compare for non-NaN)
__device__ __forceinline__ unsigned int ord_f32(float d) {
  unsigned int b = __float_as_uint(d);
  return b ^ ((b >> 31) ? 0xFFFFFFFFu : 0x80000000u);
}

// ---- eigen-ratio tail (R11/R12-proven: absmax 0.0 measured) ----
__device__ __forceinline__ double eigen_ratio_tail(
    float cxx, float cyy, float czz, float cxy, float cxz, float cyz,
    float k1) {
  double a   = (double)__fmul_rn(cxx, k1), b = (double)__fmul_rn(cyy, k1);
  double c2  = (double)__fmul_rn(czz, k1);
  double dxy = (double)__fmul_rn(cxy, k1), exz = (double)__fmul_rn(cxz, k1);
  double fyz = (double)__fmul_rn(cyz, k1);
  double qm = (a + b + c2) / 3.0;
  double p1 = dxy * dxy + exz * exz + fyz * fyz;
  double aa = a - qm, bb = b - qm, cc = c2 - qm;
  double p2 = aa * aa + bb * bb + cc * cc + 2.0 * p1;
  if (p2 <= 0.0) return 1.0;
  double p  = sqrt(p2 / 6.0);
  double ip = 1.0 / p;
  double b00 = aa * ip, b11 = bb * ip, b22 = cc * ip;
  double b01 = dxy * ip, b02 = exz * ip, b12 = fyz * ip;
  double detB = b00 * (b11 * b22 - b12 * b12)
              - b01 * (b01 * b22 - b12 * b02)
              + b02 * (b01 * b12 - b11 * b02);
  double r = 0.5 * detB;
  r = fmin(1.0, fmax(-1.0, r));
  const double dcl = 2.0 * r;
  float phif = acosf((float)r) * (1.0f / 3.0f);
  double y0 = 2.0 * (double)cosf(phif);
  double y2 = 2.0 * (double)cosf(phif + 2.0943951f);
#pragma unroll
  for (int it = 0; it < 3; ++it) {
    double g0 = 3.0 * (y0 * y0 - 1.0);
    if (fabs(g0) > 1e-4) y0 -= (y0 * y0 * y0 - 3.0 * y0 - dcl) / g0;
    double g2 = 3.0 * (y2 * y2 - 1.0);
    if (fabs(g2) > 1e-4) y2 -= (y2 * y2 * y2 - 3.0 * y2 - dcl) / g2;
  }
  double e0 = qm + p * y0;
  double e2v = qm + p * y2;
  double e1 = 3.0 * qm - e0 - e2v;
  return e0 / e1;
}

// batched top-16 update: 8 new distances d[0..7] vs sorted-asc bd[0..15]
__device__ __forceinline__ void topk_update(float bd[KK], float d[8]) {
  CSWAP_DESC(d[0], d[1]) CSWAP_DESC(d[2], d[3]) CSWAP_DESC(d[4], d[5]) CSWAP_DESC(d[6], d[7])
  CSWAP_DESC(d[0], d[2]) CSWAP_DESC(d[1], d[3]) CSWAP_DESC(d[4], d[6]) CSWAP_DESC(d[5], d[7])
  CSWAP_DESC(d[1], d[2]) CSWAP_DESC(d[5], d[6])
  CSWAP_DESC(d[0], d[4]) CSWAP_DESC(d[1], d[5]) CSWAP_DESC(d[2], d[6]) CSWAP_DESC(d[3], d[7])
  CSWAP_DESC(d[2], d[4]) CSWAP_DESC(d[3], d[5])
  CSWAP_DESC(d[1], d[2]) CSWAP_DESC(d[3], d[4]) CSWAP_DESC(d[5], d[6])
#pragma unroll
  for (int i = 0; i < 8; ++i) bd[8 + i] = fminf(bd[8 + i], d[i]);
#pragma unroll
  for (int i = 0; i < 8; ++i)  CSWAP_ASC(bd[i], bd[i + 8])
#pragma unroll
  for (int i = 0; i < 4; ++i)  CSWAP_ASC(bd[i], bd[i + 4])
#pragma unroll
  for (int i = 8; i < 12; ++i) CSWAP_ASC(bd[i], bd[i + 4])
#pragma unroll
  for (int g = 0; g < 4; ++g) {
    CSWAP_ASC(bd[4 * g + 0], bd[4 * g + 2]) CSWAP_ASC(bd[4 * g + 1], bd[4 * g + 3])
    CSWAP_ASC(bd[4 * g + 0], bd[4 * g + 1]) CSWAP_ASC(bd[4 * g + 2], bd[4 * g + 3])
  }
}

__global__ void prep_kernel(const float* __restrict__ x,
                            float4* __restrict__ cand) {
  int i = blockIdx.x * 256 + threadIdx.x;
  if (i < NPTS) {
    float px = x[3 * i + 0], py = x[3 * i + 1], pz = x[3 * i + 2];
    cand[i] = make_float4(px, py, pz, ref_sq(px, py, pz));
  }
}

// ---------------- kA: tau = 16th-smallest FAST-d over [0,2048) --------------
// Round 13: two independent network chains per wave (bdA/bdB, 16 cands per
// step) break the serial topk dependency (tau was ~85us at a ~19us VALU
// floor); fast_d2 (tau value needs no ref-exactness -- fail-safe). Exact
// union-merge at the end keeps tau = exact 16th of the sample by fast-d.
__global__ __launch_bounds__(512) void tau_stage_kernel(
    const float4* __restrict__ cand, float* __restrict__ tauArr) {
  __shared__ __align__(16) char smem[NTS * 64 * 17 * 4];   // 34,816 B
  float4* samp = (float4*)smem;                            // [2048] phases 1-2
  float (*s_t)[64][17] = (float (*)[64][17])smem;          // [8][64][17] 3-4
  const int tid   = threadIdx.x;
  const int lane  = tid & 63;
  const int w     = __builtin_amdgcn_readfirstlane(tid >> 6);
  const int group = blockIdx.x;              // 0..511
  const int batch = group >> 7;
  const int qbase = (group & 127) * QPB;
  const float4* __restrict__ Cb = cand + (size_t)batch * NP;

  const float4 q = Cb[qbase + lane];
  const float qx = q.x, qy = q.y, qz = q.z, sqq = q.w;

#pragma unroll
  for (int r = 0; r < TSAMP / 512; ++r)
    samp[r * 512 + tid] = Cb[r * 512 + tid];
  __syncthreads();

  float bdA[KK], bdB[KK];
#pragma unroll
  for (int t = 0; t < KK; ++t) { bdA[t] = 3.4e38f; bdB[t] = 3.4e38f; }

  const int j0 = w * TCH;
  for (int jj = 0; jj < TCH; jj += 16) {
    const float4* xp = samp + (j0 + jj);     // uniform LDS addr: broadcast
    float4 c[16];
#pragma unroll
    for (int u = 0; u < 16; ++u) c[u] = xp[u];
    float dA[8], dB[8];
#pragma unroll
    for (int u = 0; u < 8; ++u) dA[u] = fast_d2(qx, qy, qz, sqq, c[u]);
#pragma unroll
    for (int u = 0; u < 8; ++u) dB[u] = fast_d2(qx, qy, qz, sqq, c[8 + u]);
    topk_update(bdA, dA);                    // two independent chains:
    topk_update(bdB, dB);                    // scheduler interleaves
  }
  // exact union merge: top-16 of (A u B)
  topk_update(bdA, &bdB[0]);
  topk_update(bdA, &bdB[8]);
  __syncthreads();

#pragma unroll
  for (int t = 0; t < KK; ++t) s_t[w][lane][t] = bdA[t];
  __syncthreads();

  if (w == 0) {
    float md[KK];
#pragma unroll
    for (int t = 0; t < KK; ++t) md[t] = s_t[0][lane][t];
#pragma unroll
    for (int s2 = 1; s2 < NTS; ++s2) {
      float d[KK];
#pragma unroll
      for (int t = 0; t < KK; ++t) d[t] = s_t[s2][lane][t];
      topk_update(md, &d[0]);
      topk_update(md, &d[8]);
    }
    tauArr[batch * NP + qbase + lane] = md[KK - 1];
  }
}

// ---------------- kB: fused filter + parallel select + eigen ----------------
__global__ __launch_bounds__(512) void filter_select_kernel(
    const float4* __restrict__ cand, const float* __restrict__ tauArr,
    float* __restrict__ out) {
  extern __shared__ __align__(16) char smem[];
  unsigned short* s_idx = (unsigned short*)smem;                 // phase 1
  unsigned long long* keys = (unsigned long long*)smem;          // phase 2+
  unsigned short* s_cnt = (unsigned short*)(smem + 70144);       // [8][64]

  const int tid   = threadIdx.x;
  const int lane  = tid & 63;
  const int w     = __builtin_amdgcn_readfirstlane(tid >> 6);
  const int group = blockIdx.x;              // 0..511
  const int batch = group >> 7;
  const int qbase = (group & 127) * QPB;
  const float4* __restrict__ Cb = cand + (size_t)batch * NP;

  // ---- phase 1: filter (R8-proven body; fast_d2 vs margined tau) ----
  {
    const int j0 = w * BCH;
    const float tau = tauArr[batch * NP + qbase + lane] + TAU_MARGIN;
    const float4 q = Cb[qbase + lane];
    const float qx = q.x, qy = q.y, qz = q.z, sqq = q.w;

    unsigned short* Srow = &s_idx[w * SCH + lane * SROW];
    int cnt = 0;
    for (int jj = 0; jj < BCH; jj += 16) {
      const float4* xp = Cb + (j0 + jj);     // wave-uniform address
      float4 c[16];
#pragma unroll
      for (int u = 0; u < 16; ++u) c[u] = xp[u];   // 16 loads in flight
#pragma unroll
      for (int u = 0; u < 16; ++u) {
        float d = fast_d2(qx, qy, qz, sqq, c[u]);
        if (d <= tau) {
          if (cnt < CAP) Srow[1 + cnt] = (unsigned short)(j0 + jj + u);
          ++cnt;                             // count ALL survivors
        }
      }
    }
    s_cnt[w * 64 + lane] = (unsigned short)cnt;
  }
  __syncthreads();

  // ---- phase 2: 8 threads/query; thread (q,p) -> chunk p's top-16 keys ----
  const int qlq = tid >> 3;                  // query-in-group 0..63
  const int pch = tid & 7;                   // source chunk 0..7
  unsigned long long slots[KK];
#pragma unroll
  for (int t = 0; t < KK; ++t) slots[t] = PADKEY;
  {
    const float4 qq = Cb[qbase + qlq];
    const float q2x = qq.x, q2y = qq.y, q2z = qq.z, sq2 = qq.w;
    const unsigned short* row = &s_idx[pch * SCH + qlq * SROW + 1];
    int cnl = (int)s_cnt[pch * 64 + qlq];
    if (cnl > CAP) cnl = CAP;                // overflow query goes fs anyway
    for (int e = 0; e < cnl; e += 8) {
      unsigned long long kv[8];
#pragma unroll
      for (int u = 0; u < 8; ++u) {
        const bool ok = (e + u) < cnl;
        const int j = ok ? (int)row[e + u] : 0;
        const float dd = ref_d2q(q2x, q2y, q2z, sq2, Cb[j]);  // EXACT re-rank
        kv[u] = ok ? ((((unsigned long long)ord_f32(dd)) << 32) |
                      (unsigned int)j)
                   : PADKEY;
      }
#pragma unroll
      for (int u = 0; u < 8; ++u) {
        const unsigned long long k = kv[u];
        if (k < slots[KK - 1]) {
#pragma unroll
          for (int t = KK - 1; t >= 1; --t) {
            unsigned long long lo =
                (slots[t] < k) ? slots[t] : k;           // min
            slots[t] = (slots[t - 1] > lo) ? slots[t - 1] : lo;  // max
          }
          slots[0] = (slots[0] < k) ? slots[0] : k;
        }
      }
    }
  }
  __syncthreads();                           // all s_idx reads complete

  // write keys (overlays s_idx region); padded strides kill bank conflicts
#pragma unroll
  for (int t = 0; t < KK; ++t)
    keys[qlq * KQS + pch * KCH + t] = slots[t];
  __syncthreads();

  // ---- phase 3+4: one thread per query: merge + covariance + eigen ----
  if (tid < QPB) {
    const int ql = tid;
    const int qg = batch * NP + qbase + ql;
    const float4 qq = Cb[qbase + ql];
    const float q2x = qq.x, q2y = qq.y, q2z = qq.z, sq2 = qq.w;

    int total = 0;
    bool fs = false;
#pragma unroll
    for (int p = 0; p < NBCH; ++p) {
      const int c = (int)s_cnt[p * 64 + ql];
      if (c > CAP) fs = true;
      total += c;
    }
    if (total < KK) fs = true;

    int mjr[KK];
    if (!fs) {
      // 8-way tournament merge of sorted key lists; 16 outputs.
      const unsigned long long* kq = keys + ql * KQS;
      int head[NBCH];
#pragma unroll
      for (int p = 0; p < NBCH; ++p) head[p] = 0;
#pragma unroll
      for (int t = 0; t < KK; ++t) {
        unsigned long long best = PADKEY;
        int bp = 0;
#pragma unroll
        for (int p = 0; p < NBCH; ++p) {
          const unsigned long long k =
              (head[p] < KK) ? kq[p * KCH + head[p]] : PADKEY;
          if (k < best) { best = k; bp = p; }
        }
        head[bp]++;
        mjr[t] = (int)(best & 0xFFFFull);    // j (real keys: < 8192)
      }
    } else {
      // exact full-scan insertion with index tracking (verbatim-proven)
      float md[KK];
#pragma unroll
      for (int t = 0; t < KK; ++t) { md[t] = 3.4e38f; mjr[t] = 0; }
      for (int j = 0; j < NP; ++j) {
        float d = ref_d2q(q2x, q2y, q2z, sq2, Cb[j]);
        if (d < md[KK - 1]) {
          bool c0 = d < md[0];
#pragma unroll
          for (int t = KK - 1; t >= 1; --t) {
            bool cl = d < md[t];
            bool cp = d < md[t - 1];
            float nv = fmaxf(md[t - 1], fminf(md[t], d));
            mjr[t] = cl ? (cp ? mjr[t - 1] : j) : mjr[t];
            md[t] = nv;
          }
          mjr[0] = c0 ? j : mjr[0];
          md[0] = fminf(md[0], d);
        }
      }
    }

    // covariance in merged (d,j) order == proven chain order
    float4 pts[KK];
#pragma unroll
    for (int s = 0; s < KK; ++s) pts[s] = Cb[mjr[s]];

    float sx = 0.f, sy = 0.f, sz = 0.f;
#pragma unroll
    for (int s = 0; s < KK; ++s) {
      sx = __fadd_rn(sx, pts[s].x);
      sy = __fadd_rn(sy, pts[s].y);
      sz = __fadd_rn(sz, pts[s].z);
    }
    const float k1 = 1.0f / KK;
    const float mx = sx * k1, my = sy * k1, mz = sz * k1;

    float cxx = 0.f, cxy = 0.f, cxz = 0.f, cyy = 0.f, cyz = 0.f, czz = 0.f;
#pragma unroll
    for (int s = 0; s < KK; ++s) {
      float dx = __fsub_rn(pts[s].x, mx);
      float dy = __fsub_rn(pts[s].y, my);
      float dz = __fsub_rn(pts[s].z, mz);
      cxx = __fadd_rn(cxx, __fmul_rn(dx, dx));
      cxy = __fadd_rn(cxy, __fmul_rn(dx, dy));
      cxz = __fadd_rn(cxz, __fmul_rn(dx, dz));
      cyy = __fadd_rn(cyy, __fmul_rn(dy, dy));
      cyz = __fadd_rn(cyz, __fmul_rn(dy, dz));
      czz = __fadd_rn(czz, __fmul_rn(dz, dz));
    }

    out[qg] = (float)eigen_ratio_tail(cxx, cyy, czz, cxy, cxz, cyz, k1);
  }
}

// ---------------- fallback: verbatim single kernel (proven pass) ------------
__global__ __launch_bounds__(512, 4) void knn_eigen_fallback(
    const float4* __restrict__ cand, float* __restrict__ out) {
  __shared__ unsigned short s_j[8][QPB][18];

  const int tid   = threadIdx.x;
  const int lane  = tid & 63;
  const int w     = __builtin_amdgcn_readfirstlane(tid >> 6);
  const int batch = blockIdx.x >> 7;
  const int qbase = (blockIdx.x & 127) * QPB;
  const int FCH   = NP / 8;   // 1024

  const float4* __restrict__ Cb = cand + (size_t)batch * NP;

  const float4 q = Cb[qbase + lane];
  const float qx = q.x, qy = q.y, qz = q.z, sqq = q.w;

  float bd[KK];
#pragma unroll
  for (int t = 0; t < KK; ++t) bd[t] = 3.4e38f;

  const int j0 = w * FCH;
  for (int jj = 0; jj < FCH; jj += 8) {
    const float4* xp = Cb + (j0 + jj);
    float4 c[8];
#pragma unroll
    for (int u = 0; u < 8; ++u) c[u] = xp[u];
    float d[8];
#pragma unroll
    for (int u = 0; u < 8; ++u) d[u] = ref_d2q(qx, qy, qz, sqq, c[u]);
    topk_update(bd, d);
  }

  const float T = bd[KK - 1];
  int cnt = 0;
  for (int jj = 0; jj < FCH; jj += 8) {
    const float4* xp = Cb + (j0 + jj);
    float4 c[8];
#pragma unroll
    for (int u = 0; u < 8; ++u) c[u] = xp[u];
#pragma unroll
    for (int u = 0; u < 8; ++u) {
      float d = ref_d2q(qx, qy, qz, sqq, c[u]);
      if (d <= T && cnt < KK) {
        s_j[w][lane][cnt] = (unsigned short)(j0 + jj + u);
        cnt++;
      }
    }
  }
  __syncthreads();

  if (tid < QPB) {
    const float4 qq = Cb[qbase + tid];
    const float q2x = qq.x, q2y = qq.y, q2z = qq.z, sq2 = qq.w;
    float md[KK]; int mj[KK];
#pragma unroll
    for (int t = 0; t < KK; ++t) { md[t] = 3.4e38f; mj[t] = 0; }
    for (int cch = 0; cch < 8; ++cch) {
      const unsigned int* rowp = (const unsigned int*)&s_j[cch][tid][0];
#pragma unroll
      for (int sp = 0; sp < KK / 2; ++sp) {
        unsigned int pk = rowp[sp];
#pragma unroll
        for (int half = 0; half < 2; ++half) {
          int j = (half == 0) ? (int)(pk & 0xFFFFu) : (int)(pk >> 16);
          float d = ref_d2q(q2x, q2y, q2z, sq2, Cb[j]);
          if (d < md[KK - 1]) {
            bool c0 = d < md[0];
#pragma unroll
            for (int t = KK - 1; t >= 1; --t) {
              bool cl = d < md[t];
              bool cp = d < md[t - 1];
              float nv = fmaxf(md[t - 1], fminf(md[t], d));
              mj[t] = cl ? (cp ? mj[t - 1] : j) : mj[t];
              md[t] = nv;
            }
            mj[0] = c0 ? j : mj[0];
            md[0] = fminf(md[0], d);
          }
        }
      }
    }
    float sx = 0.f, sy = 0.f, sz = 0.f;
#pragma unroll
    for (int s = 0; s < KK; ++s) {
      float4 pp = Cb[mj[s]];
      sx = __fadd_rn(sx, pp.x);
      sy = __fadd_rn(sy, pp.y);
      sz = __fadd_rn(sz, pp.z);
    }
    const float k1 = 1.0f / KK;
    const float mx = sx * k1, my = sy * k1, mz = sz * k1;
    float cxx = 0.f, cxy = 0.f, cxz = 0.f, cyy = 0.f, cyz = 0.f, czz = 0.f;
#pragma unroll
    for (int s = 0; s < KK; ++s) {
      float4 pp = Cb[mj[s]];
      float dx = __fsub_rn(pp.x, mx);
      float dy = __fsub_rn(pp.y, my);
      float dz = __fsub_rn(pp.z, mz);
      cxx = __fadd_rn(cxx, __fmul_rn(dx, dx));
      cxy = __fadd_rn(cxy, __fmul_rn(dx, dy));
      cxz = __fadd_rn(cxz, __fmul_rn(dx, dz));
      cyy = __fadd_rn(cyy, __fmul_rn(dy, dy));
      cyz = __fadd_rn(cyz, __fmul_rn(dy, dz));
      czz = __fadd_rn(czz, __fmul_rn(dz, dz));
    }
    out[(size_t)batch * NP + qbase + tid] =
        (float)eigen_ratio_tail(cxx, cyy, czz, cxy, cxz, cyz, k1);
  }
}

extern "C" void kernel_launch(void* const* d_in, const int* in_sizes, int n_in,
                              void* d_out, int out_size, void* d_ws, size_t ws_size,
                              hipStream_t stream) {
  const float* x = (const float*)d_in[0];
  float* out = (float*)d_out;
  float4* cand = (float4*)d_ws;                                   // 512 KB
  float* tauArr = (float*)((char*)d_ws + (size_t)NPTS * sizeof(float4)); // 128 KB
  const size_t need = (size_t)NPTS * sizeof(float4) +
                      (size_t)NPTS * sizeof(float);               // 640 KB

  prep_kernel<<<dim3(NPTS / 256), dim3(256), 0, stream>>>(x, cand);
  if (ws_size >= need) {
    tau_stage_kernel<<<dim3(512), dim3(512), 0, stream>>>(cand, tauArr);
    const size_t fs_lds = 70144 + 1024;      // keys/s_idx union + s_cnt
    filter_select_kernel<<<dim3(512), dim3(512), fs_lds, stream>>>(
        cand, tauArr, out);
  } else {
    knn_eigen_fallback<<<dim3(NPTS / QPB), dim3(512), 0, stream>>>(cand, out);
  }
}

// Round 14
// 186.437 us; speedup vs baseline: 1.4001x; 1.0060x over previous
//
#include <hip/hip_runtime.h>
#include <math.h>

#define NB 4
#define NP 8192
#define KK 16
#define QPB 64
#define NPTS (NB * NP)

// ---- geometry (round 14) ----
#define TSAMP 1024            // tau sample = candidates [0,1024)  (was 2048)
#define TTCH 128              // tau subchunk per wave (1024/8)
#define NTS 8                 // tau: 8 waves per query-group
#define BCH 1024              // filter chunk size
#define NBCH 8                // 8 chunks cover [0,8192)
#define CAP 62                // per-(query,chunk) capacity: P(overflow)~1e-11
#define SROW 66               // u16 per (chunk,query) LDS row: [0]=unused,[1..62]=idx
                              // (66 u16 = 33 dwords, odd -> conflict-free)
#define SCH (64 * SROW + 2)   // LDS chunk stride in u16 (=4226)
#define KCH 17                // keys: u64 per chunk-list (16 + 1 pad)
#define KQS (NBCH * KCH + 1)  // keys: u64 per query block (137)
#define PADKEY 0xFFFFFFFFFFFFFFFFull
#define TAU_MARGIN 2.5e-4f    // >= 2x the |fast_d2-ref_d2| bound (~3.4e-5)
// LDS (dynamic, 71,168B): [0,70144) = union{ s_idx u16 8x4226 (67,616B,
// filter phase), keys u64[64][137] (70,144B, select phase, overlays after
// barrier) }; [70144,71168) = s_cnt u16[8][64].
//
// Correctness chain (fail-safe, independent of tau's value):
//  S = {j: fast_d(j) <= tau + MARGIN}, tau = 16th-smallest FAST-d over the
//  1024-sample. tau >= d_ref(16th of sample) - 3.4e-5 >= d_ref(16) - 3.4e-5;
//  for j in ref-top-16: fast_d(j) <= d_ref(16) + 3.4e-5 <= tau + 6.8e-5
//  <= tau + MARGIN => top-16 subset of S. Phase 2 re-ranks S with EXACT
//  ref_d; key=(orderable(d)<<32)|j reproduces the proven chain's total order
//  (d asc, j asc) -> identical top-16 in identical order (absmax 0.0,
//  R12/R13). Chunk cnt > CAP or total < 16 => proven exact full-scan.
//  R1 lesson: 1024-sample tau gives ~2x survivors (mean 128/query) with a
//  fat Gamma(16) tail -- CAP=62 puts P(chunk>CAP) ~ 1e-11 (~3e-6 full-scans
//  expected; R1 failed because overflow was silently dropped, not flagged).

// comparator macros (exact: min/max introduce no rounding)
#define CSWAP_DESC(a, b) { float _lo = fminf(a, b); float _hi = fmaxf(a, b); a = _hi; b = _lo; }
#define CSWAP_ASC(a, b)  { float _lo = fminf(a, b); float _hi = fmaxf(a, b); a = _lo; b = _hi; }

__device__ __forceinline__ float ref_sq(float x, float y, float z) {
  return __fadd_rn(__fadd_rn(__fmul_rn(x, x), __fmul_rn(y, y)), __fmul_rn(z, z));
}

__device__ __forceinline__ float ref_d2q(float qx, float qy, float qz, float sqq,
                                         float4 c) {
  float dot = __fadd_rn(__fadd_rn(__fmul_rn(qx, c.x), __fmul_rn(qy, c.y)),
                        __fmul_rn(qz, c.z));
  float s = __fadd_rn(sqq, c.w);
  return __fmaf_rn(-2.0f, dot, s);
}

// fast 5-op distance; |fast - ref| <= ~3.4e-5 on this data range.
__device__ __forceinline__ float fast_d2(float qx, float qy, float qz, float sqq,
                                         float4 c) {
  float dot = __fmaf_rn(qz, c.z, __fmaf_rn(qy, c.y, __fmul_rn(qx, c.x)));
  float s = __fadd_rn(sqq, c.w);
  return __fmaf_rn(-2.0f, dot, s);
}

// order-preserving float->u32 (total order == float compare for non-NaN)
__device__ __forceinline__ unsigned int ord_f32(float d) {
  unsigned int b = __float_as_uint(d);
  return b ^ ((b >> 31) ? 0xFFFFFFFFu : 0x80000000u);
}

// ---- eigen-ratio tail (R11/R12/R13-proven: absmax 0.0 measured) ----
__device__ __forceinline__ double eigen_ratio_tail(
    float cxx, float cyy, float czz, float cxy, float cxz, float cyz,
    float k1) {
  double a   = (double)__fmul_rn(cxx, k1), b = (double)__fmul_rn(cyy, k1);
  double c2  = (double)__fmul_rn(czz, k1);
  double dxy = (double)__fmul_rn(cxy, k1), exz = (double)__fmul_rn(cxz, k1);
  double fyz = (double)__fmul_rn(cyz, k1);
  double qm = (a + b + c2) / 3.0;
  double p1 = dxy * dxy + exz * exz + fyz * fyz;
  double aa = a - qm, bb = b - qm, cc = c2 - qm;
  double p2 = aa * aa + bb * bb + cc * cc + 2.0 * p1;
  if (p2 <= 0.0) return 1.0;
  double p  = sqrt(p2 / 6.0);
  double ip = 1.0 / p;
  double b00 = aa * ip, b11 = bb * ip, b22 = cc * ip;
  double b01 = dxy * ip, b02 = exz * ip, b12 = fyz * ip;
  double detB = b00 * (b11 * b22 - b12 * b12)
              - b01 * (b01 * b22 - b12 * b02)
              + b02 * (b01 * b12 - b11 * b02);
  double r = 0.5 * detB;
  r = fmin(1.0, fmax(-1.0, r));
  const double dcl = 2.0 * r;
  float phif = acosf((float)r) * (1.0f / 3.0f);
  double y0 = 2.0 * (double)cosf(phif);
  double y2 = 2.0 * (double)cosf(phif + 2.0943951f);
#pragma unroll
  for (int it = 0; it < 3; ++it) {
    double g0 = 3.0 * (y0 * y0 - 1.0);
    if (fabs(g0) > 1e-4) y0 -= (y0 * y0 * y0 - 3.0 * y0 - dcl) / g0;
    double g2 = 3.0 * (y2 * y2 - 1.0);
    if (fabs(g2) > 1e-4) y2 -= (y2 * y2 * y2 - 3.0 * y2 - dcl) / g2;
  }
  double e0 = qm + p * y0;
  double e2v = qm + p * y2;
  double e1 = 3.0 * qm - e0 - e2v;
  return e0 / e1;
}

// batched top-16 update: 8 new distances d[0..7] vs sorted-asc bd[0..15]
__device__ __forceinline__ void topk_update(float bd[KK], float d[8]) {
  CSWAP_DESC(d[0], d[1]) CSWAP_DESC(d[2], d[3]) CSWAP_DESC(d[4], d[5]) CSWAP_DESC(d[6], d[7])
  CSWAP_DESC(d[0], d[2]) CSWAP_DESC(d[1], d[3]) CSWAP_DESC(d[4], d[6]) CSWAP_DESC(d[5], d[7])
  CSWAP_DESC(d[1], d[2]) CSWAP_DESC(d[5], d[6])
  CSWAP_DESC(d[0], d[4]) CSWAP_DESC(d[1], d[5]) CSWAP_DESC(d[2], d[6]) CSWAP_DESC(d[3], d[7])
  CSWAP_DESC(d[2], d[4]) CSWAP_DESC(d[3], d[5])
  CSWAP_DESC(d[1], d[2]) CSWAP_DESC(d[3], d[4]) CSWAP_DESC(d[5], d[6])
#pragma unroll
  for (int i = 0; i < 8; ++i) bd[8 + i] = fminf(bd[8 + i], d[i]);
#pragma unroll
  for (int i = 0; i < 8; ++i)  CSWAP_ASC(bd[i], bd[i + 8])
#pragma unroll
  for (int i = 0; i < 4; ++i)  CSWAP_ASC(bd[i], bd[i + 4])
#pragma unroll
  for (int i = 8; i < 12; ++i) CSWAP_ASC(bd[i], bd[i + 4])
#pragma unroll
  for (int g = 0; g < 4; ++g) {
    CSWAP_ASC(bd[4 * g + 0], bd[4 * g + 2]) CSWAP_ASC(bd[4 * g + 1], bd[4 * g + 3])
    CSWAP_ASC(bd[4 * g + 0], bd[4 * g + 1]) CSWAP_ASC(bd[4 * g + 2], bd[4 * g + 3])
  }
}

__global__ void prep_kernel(const float* __restrict__ x,
                            float4* __restrict__ cand) {
  int i = blockIdx.x * 256 + threadIdx.x;
  if (i < NPTS) {
    float px = x[3 * i + 0], py = x[3 * i + 1], pz = x[3 * i + 2];
    cand[i] = make_float4(px, py, pz, ref_sq(px, py, pz));
  }
}

// ---------------- kA: tau = 16th-smallest FAST-d over [0,1024) --------------
// R13 structure with half the sample (R1's geometry, now safe: overflow is
// flagged -> full-scan, not silently dropped). tau errors are harmless.
__global__ __launch_bounds__(512) void tau_stage_kernel(
    const float4* __restrict__ cand, float* __restrict__ tauArr) {
  __shared__ __align__(16) char smem[NTS * 64 * 17 * 4];   // 34,816 B
  float4* samp = (float4*)smem;                            // [1024] phases 1-2
  float (*s_t)[64][17] = (float (*)[64][17])smem;          // [8][64][17] 3-4
  const int tid   = threadIdx.x;
  const int lane  = tid & 63;
  const int w     = __builtin_amdgcn_readfirstlane(tid >> 6);
  const int group = blockIdx.x;              // 0..511
  const int batch = group >> 7;
  const int qbase = (group & 127) * QPB;
  const float4* __restrict__ Cb = cand + (size_t)batch * NP;

  const float4 q = Cb[qbase + lane];
  const float qx = q.x, qy = q.y, qz = q.z, sqq = q.w;

#pragma unroll
  for (int r = 0; r < TSAMP / 512; ++r)
    samp[r * 512 + tid] = Cb[r * 512 + tid];
  __syncthreads();

  float bdA[KK], bdB[KK];
#pragma unroll
  for (int t = 0; t < KK; ++t) { bdA[t] = 3.4e38f; bdB[t] = 3.4e38f; }

  const int j0 = w * TTCH;
  for (int jj = 0; jj < TTCH; jj += 16) {
    const float4* xp = samp + (j0 + jj);     // uniform LDS addr: broadcast
    float4 c[16];
#pragma unroll
    for (int u = 0; u < 16; ++u) c[u] = xp[u];
    float dA[8], dB[8];
#pragma unroll
    for (int u = 0; u < 8; ++u) dA[u] = fast_d2(qx, qy, qz, sqq, c[u]);
#pragma unroll
    for (int u = 0; u < 8; ++u) dB[u] = fast_d2(qx, qy, qz, sqq, c[8 + u]);
    topk_update(bdA, dA);                    // two independent chains
    topk_update(bdB, dB);
  }
  topk_update(bdA, &bdB[0]);                 // exact union merge
  topk_update(bdA, &bdB[8]);
  __syncthreads();

#pragma unroll
  for (int t = 0; t < KK; ++t) s_t[w][lane][t] = bdA[t];
  __syncthreads();

  if (w == 0) {
    float md[KK];
#pragma unroll
    for (int t = 0; t < KK; ++t) md[t] = s_t[0][lane][t];
#pragma unroll
    for (int s2 = 1; s2 < NTS; ++s2) {
      float d[KK];
#pragma unroll
      for (int t = 0; t < KK; ++t) d[t] = s_t[s2][lane][t];
      topk_update(md, &d[0]);
      topk_update(md, &d[8]);
    }
    tauArr[batch * NP + qbase + lane] = md[KK - 1];
  }
}

// ---------------- kB: fused filter + parallel select + eigen ----------------
__global__ __launch_bounds__(512) void filter_select_kernel(
    const float4* __restrict__ cand, const float* __restrict__ tauArr,
    float* __restrict__ out) {
  extern __shared__ __align__(16) char smem[];
  unsigned short* s_idx = (unsigned short*)smem;                 // phase 1
  unsigned long long* keys = (unsigned long long*)smem;          // phase 2+
  unsigned short* s_cnt = (unsigned short*)(smem + 70144);       // [8][64]

  const int tid   = threadIdx.x;
  const int lane  = tid & 63;
  const int w     = __builtin_amdgcn_readfirstlane(tid >> 6);
  const int group = blockIdx.x;              // 0..511
  const int batch = group >> 7;
  const int qbase = (group & 127) * QPB;
  const float4* __restrict__ Cb = cand + (size_t)batch * NP;

  // ---- phase 1: filter (R8-proven body; fast_d2 vs margined tau) ----
  {
    const int j0 = w * BCH;
    const float tau = tauArr[batch * NP + qbase + lane] + TAU_MARGIN;
    const float4 q = Cb[qbase + lane];
    const float qx = q.x, qy = q.y, qz = q.z, sqq = q.w;

    unsigned short* Srow = &s_idx[w * SCH + lane * SROW];
    int cnt = 0;
    for (int jj = 0; jj < BCH; jj += 16) {
      const float4* xp = Cb + (j0 + jj);     // wave-uniform address
      float4 c[16];
#pragma unroll
      for (int u = 0; u < 16; ++u) c[u] = xp[u];   // 16 loads in flight
#pragma unroll
      for (int u = 0; u < 16; ++u) {
        float d = fast_d2(qx, qy, qz, sqq, c[u]);
        if (d <= tau) {
          if (cnt < CAP) Srow[1 + cnt] = (unsigned short)(j0 + jj + u);
          ++cnt;                             // count ALL survivors
        }
      }
    }
    s_cnt[w * 64 + lane] = (unsigned short)cnt;
  }
  __syncthreads();

  // ---- phase 2: 8 threads/query; thread (q,p) -> chunk p's top-16 keys ----
  const int qlq = tid >> 3;                  // query-in-group 0..63
  const int pch = tid & 7;                   // source chunk 0..7
  unsigned long long slots[KK];
#pragma unroll
  for (int t = 0; t < KK; ++t) slots[t] = PADKEY;
  {
    const float4 qq = Cb[qbase + qlq];
    const float q2x = qq.x, q2y = qq.y, q2z = qq.z, sq2 = qq.w;
    const unsigned short* row = &s_idx[pch * SCH + qlq * SROW + 1];
    int cnl = (int)s_cnt[pch * 64 + qlq];
    if (cnl > CAP) cnl = CAP;                // overflow query goes fs anyway
    for (int e = 0; e < cnl; e += 8) {
      unsigned long long kv[8];
#pragma unroll
      for (int u = 0; u < 8; ++u) {
        const bool ok = (e + u) < cnl;
        const int j = ok ? (int)row[e + u] : 0;
        const float dd = ref_d2q(q2x, q2y, q2z, sq2, Cb[j]);  // EXACT re-rank
        kv[u] = ok ? ((((unsigned long long)ord_f32(dd)) << 32) |
                      (unsigned int)j)
                   : PADKEY;
      }
#pragma unroll
      for (int u = 0; u < 8; ++u) {
        const unsigned long long k = kv[u];
        if (k < slots[KK - 1]) {
#pragma unroll
          for (int t = KK - 1; t >= 1; --t) {
            unsigned long long lo =
                (slots[t] < k) ? slots[t] : k;           // min
            slots[t] = (slots[t - 1] > lo) ? slots[t - 1] : lo;  // max
          }
          slots[0] = (slots[0] < k) ? slots[0] : k;
        }
      }
    }
  }
  __syncthreads();                           // all s_idx reads complete

  // write keys (overlays s_idx region); padded strides kill bank conflicts
#pragma unroll
  for (int t = 0; t < KK; ++t)
    keys[qlq * KQS + pch * KCH + t] = slots[t];
  __syncthreads();

  // ---- phase 3+4: one thread per query: merge + covariance + eigen ----
  if (tid < QPB) {
    const int ql = tid;
    const int qg = batch * NP + qbase + ql;
    const float4 qq = Cb[qbase + ql];
    const float q2x = qq.x, q2y = qq.y, q2z = qq.z, sq2 = qq.w;

    int total = 0;
    bool fs = false;
#pragma unroll
    for (int p = 0; p < NBCH; ++p) {
      const int c = (int)s_cnt[p * 64 + ql];
      if (c > CAP) fs = true;
      total += c;
    }
    if (total < KK) fs = true;

    int mjr[KK];
    if (!fs) {
      // 8-way tournament merge of sorted key lists; 16 outputs.
      const unsigned long long* kq = keys + ql * KQS;
      int head[NBCH];
#pragma unroll
      for (int p = 0; p < NBCH; ++p) head[p] = 0;
#pragma unroll
      for (int t = 0; t < KK; ++t) {
        unsigned long long best = PADKEY;
        int bp = 0;
#pragma unroll
        for (int p = 0; p < NBCH; ++p) {
          const unsigned long long k =
              (head[p] < KK) ? kq[p * KCH + head[p]] : PADKEY;
          if (k < best) { best = k; bp = p; }
        }
        head[bp]++;
        mjr[t] = (int)(best & 0xFFFFull);    // j (real keys: < 8192)
      }
    } else {
      // exact full-scan insertion with index tracking (verbatim-proven)
      float md[KK];
#pragma unroll
      for (int t = 0; t < KK; ++t) { md[t] = 3.4e38f; mjr[t] = 0; }
      for (int j = 0; j < NP; ++j) {
        float d = ref_d2q(q2x, q2y, q2z, sq2, Cb[j]);
        if (d < md[KK - 1]) {
          bool c0 = d < md[0];
#pragma unroll
          for (int t = KK - 1; t >= 1; --t) {
            bool cl = d < md[t];
            bool cp = d < md[t - 1];
            float nv = fmaxf(md[t - 1], fminf(md[t], d));
            mjr[t] = cl ? (cp ? mjr[t - 1] : j) : mjr[t];
            md[t] = nv;
          }
          mjr[0] = c0 ? j : mjr[0];
          md[0] = fminf(md[0], d);
        }
      }
    }

    // covariance in merged (d,j) order == proven chain order
    float4 pts[KK];
#pragma unroll
    for (int s = 0; s < KK; ++s) pts[s] = Cb[mjr[s]];

    float sx = 0.f, sy = 0.f, sz = 0.f;
#pragma unroll
    for (int s = 0; s < KK; ++s) {
      sx = __fadd_rn(sx, pts[s].x);
      sy = __fadd_rn(sy, pts[s].y);
      sz = __fadd_rn(sz, pts[s].z);
    }
    const float k1 = 1.0f / KK;
    const float mx = sx * k1, my = sy * k1, mz = sz * k1;

    float cxx = 0.f, cxy = 0.f, cxz = 0.f, cyy = 0.f, cyz = 0.f, czz = 0.f;
#pragma unroll
    for (int s = 0; s < KK; ++s) {
      float dx = __fsub_rn(pts[s].x, mx);
      float dy = __fsub_rn(pts[s].y, my);
      float dz = __fsub_rn(pts[s].z, mz);
      cxx = __fadd_rn(cxx, __fmul_rn(dx, dx));
      cxy = __fadd_rn(cxy, __fmul_rn(dx, dy));
      cxz = __fadd_rn(cxz, __fmul_rn(dx, dz));
      cyy = __fadd_rn(cyy, __fmul_rn(dy, dy));
      cyz = __fadd_rn(cyz, __fmul_rn(dy, dz));
      czz = __fadd_rn(czz, __fmul_rn(dz, dz));
    }

    out[qg] = (float)eigen_ratio_tail(cxx, cyy, czz, cxy, cxz, cyz, k1);
  }
}

// ---------------- fallback: verbatim single kernel (proven pass) ------------
__global__ __launch_bounds__(512, 4) void knn_eigen_fallback(
    const float4* __restrict__ cand, float* __restrict__ out) {
  __shared__ unsigned short s_j[8][QPB][18];

  const int tid   = threadIdx.x;
  const int lane  = tid & 63;
  const int w     = __builtin_amdgcn_readfirstlane(tid >> 6);
  const int batch = blockIdx.x >> 7;
  const int qbase = (blockIdx.x & 127) * QPB;
  const int FCH   = NP / 8;   // 1024

  const float4* __restrict__ Cb = cand + (size_t)batch * NP;

  const float4 q = Cb[qbase + lane];
  const float qx = q.x, qy = q.y, qz = q.z, sqq = q.w;

  float bd[KK];
#pragma unroll
  for (int t = 0; t < KK; ++t) bd[t] = 3.4e38f;

  const int j0 = w * FCH;
  for (int jj = 0; jj < FCH; jj += 8) {
    const float4* xp = Cb + (j0 + jj);
    float4 c[8];
#pragma unroll
    for (int u = 0; u < 8; ++u) c[u] = xp[u];
    float d[8];
#pragma unroll
    for (int u = 0; u < 8; ++u) d[u] = ref_d2q(qx, qy, qz, sqq, c[u]);
    topk_update(bd, d);
  }

  const float T = bd[KK - 1];
  int cnt = 0;
  for (int jj = 0; jj < FCH; jj += 8) {
    const float4* xp = Cb + (j0 + jj);
    float4 c[8];
#pragma unroll
    for (int u = 0; u < 8; ++u) c[u] = xp[u];
#pragma unroll
    for (int u = 0; u < 8; ++u) {
      float d = ref_d2q(qx, qy, qz, sqq, c[u]);
      if (d <= T && cnt < KK) {
        s_j[w][lane][cnt] = (unsigned short)(j0 + jj + u);
        cnt++;
      }
    }
  }
  __syncthreads();

  if (tid < QPB) {
    const float4 qq = Cb[qbase + tid];
    const float q2x = qq.x, q2y = qq.y, q2z = qq.z, sq2 = qq.w;
    float md[KK]; int mj[KK];
#pragma unroll
    for (int t = 0; t < KK; ++t) { md[t] = 3.4e38f; mj[t] = 0; }
    for (int cch = 0; cch < 8; ++cch) {
      const unsigned int* rowp = (const unsigned int*)&s_j[cch][tid][0];
#pragma unroll
      for (int sp = 0; sp < KK / 2; ++sp) {
        unsigned int pk = rowp[sp];
#pragma unroll
        for (int half = 0; half < 2; ++half) {
          int j = (half == 0) ? (int)(pk & 0xFFFFu) : (int)(pk >> 16);
          float d = ref_d2q(q2x, q2y, q2z, sq2, Cb[j]);
          if (d < md[KK - 1]) {
            bool c0 = d < md[0];
#pragma unroll
            for (int t = KK - 1; t >= 1; --t) {
              bool cl = d < md[t];
              bool cp = d < md[t - 1];
              float nv = fmaxf(md[t - 1], fminf(md[t], d));
              mj[t] = cl ? (cp ? mj[t - 1] : j) : mj[t];
              md[t] = nv;
            }
            mj[0] = c0 ? j : mj[0];
            md[0] = fminf(md[0], d);
          }
        }
      }
    }
    float sx = 0.f, sy = 0.f, sz = 0.f;
#pragma unroll
    for (int s = 0; s < KK; ++s) {
      float4 pp = Cb[mj[s]];
      sx = __fadd_rn(sx, pp.x);
      sy = __fadd_rn(sy, pp.y);
      sz = __fadd_rn(sz, pp.z);
    }
    const float k1 = 1.0f / KK;
    const float mx = sx * k1, my = sy * k1, mz = sz * k1;
    float cxx = 0.f, cxy = 0.f, cxz = 0.f, cyy = 0.f, cyz = 0.f, czz = 0.f;
#pragma unroll
    for (int s = 0; s < KK; ++s) {
      float4 pp = Cb[mj[s]];
      float dx = __fsub_rn(pp.x, mx);
      float dy = __fsub_rn(pp.y, my);
      float dz = __fsub_rn(pp.z, mz);
      cxx = __fadd_rn(cxx, __fmul_rn(dx, dx));
      cxy = __fadd_rn(cxy, __fmul_rn(dx, dy));
      cxz = __fadd_rn(cxz, __fmul_rn(dx, dz));
      cyy = __fadd_rn(cyy, __fmul_rn(dy, dy));
      cyz = __fadd_rn(cyz, __fmul_rn(dy, dz));
      czz = __fadd_rn(czz, __fmul_rn(dz, dz));
    }
    out[(size_t)batch * NP + qbase + tid] =
        (float)eigen_ratio_tail(cxx, cyy, czz, cxy, cxz, cyz, k1);
  }
}

extern "C" void kernel_launch(void* const* d_in, const int* in_sizes, int n_in,
                              void* d_out, int out_size, void* d_ws, size_t ws_size,
                              hipStream_t stream) {
  const float* x = (const float*)d_in[0];
  float* out = (float*)d_out;
  float4* cand = (float4*)d_ws;                                   // 512 KB
  float* tauArr = (float*)((char*)d_ws + (size_t)NPTS * sizeof(float4)); // 128 KB
  const size_t need = (size_t)NPTS * sizeof(float4) +
                      (size_t)NPTS * sizeof(float);               // 640 KB

  prep_kernel<<<dim3(NPTS / 256), dim3(256), 0, stream>>>(x, cand);
  if (ws_size >= need) {
    tau_stage_kernel<<<dim3(512), dim3(512), 0, stream>>>(cand, tauArr);
    const size_t fs_lds = 70144 + 1024;      // keys/s_idx union + s_cnt
    filter_select_kernel<<<dim3(512), dim3(512), fs_lds, stream>>>(
        cand, tauArr, out);
  } else {
    knn_eigen_fallback<<<dim3(NPTS / QPB), dim3(512), 0, stream>>>(cand, out);
  }
}

// Round 15
// 184.674 us; speedup vs baseline: 1.4135x; 1.0096x over previous
//
#include <hip/hip_runtime.h>
#include <math.h>

#define NB 4
#define NP 8192
#define KK 16
#define QPB 64
#define NPTS (NB * NP)

// ---- geometry (round 15: tau fused into the main kernel) ----
#define TSAMP 1024            // tau sample = candidates [0,1024)
#define TTCH 128              // tau subchunk per wave (1024/8)
#define BCH 1024              // filter chunk size
#define NBCH 8                // 8 chunks cover [0,8192)
#define CAP 62                // per-(query,chunk) capacity: P(overflow)~1e-11
#define SROW 66               // u16 per (chunk,query) LDS row (odd dwords: conflict-free)
#define SCH (64 * SROW + 2)   // LDS chunk stride in u16 (=4226)
#define KCH 17                // keys: u64 per chunk-list (16 + 1 pad)
#define KQS (NBCH * KCH + 1)  // keys: u64 per query block (137)
#define PADKEY 0xFFFFFFFFFFFFFFFFull
#define TAU_MARGIN 2.5e-4f    // >= 2x the |fast_d2-ref_d2| bound (~3.4e-5)
// Dynamic LDS (71,424 B):
//   [0,70144)      phase 0: samp float4[1024] (16,384B) + s_t f32[8][64][17]
//                           at offset 16384 (34,816B)  -- disjoint
//                  phase 1: s_idx u16 8x4226 (67,616B)  -- overlays (barriered)
//                  phase 2+: keys u64[64][137] (70,144B) -- overlays (barriered)
//   [70144,71168)  s_cnt u16[8][64]
//   [71168,71424)  s_tau f32[64]
//
// Correctness chain (fail-safe, independent of tau's value):
//  tau = 16th-smallest FAST-d over the 1024-sample (bit-identical to R14's
//  separate-kernel value). S = {j: fast_d(j) <= tau + MARGIN} contains the
//  exact ref top-16 (margin >= 2x fast<->ref bound). Phase 2 re-ranks S with
//  EXACT ref_d; key=(orderable(d)<<32)|j reproduces the proven chain's total
//  order (d asc, j asc) -> identical top-16 in identical order (absmax 0.0,
//  R12-R14). Chunk cnt > CAP or total < 16 => proven exact full-scan.

// comparator macros (exact: min/max introduce no rounding)
#define CSWAP_DESC(a, b) { float _lo = fminf(a, b); float _hi = fmaxf(a, b); a = _hi; b = _lo; }
#define CSWAP_ASC(a, b)  { float _lo = fminf(a, b); float _hi = fmaxf(a, b); a = _lo; b = _hi; }

__device__ __forceinline__ float ref_sq(float x, float y, float z) {
  return __fadd_rn(__fadd_rn(__fmul_rn(x, x), __fmul_rn(y, y)), __fmul_rn(z, z));
}

__device__ __forceinline__ float ref_d2q(float qx, float qy, float qz, float sqq,
                                         float4 c) {
  float dot = __fadd_rn(__fadd_rn(__fmul_rn(qx, c.x), __fmul_rn(qy, c.y)),
                        __fmul_rn(qz, c.z));
  float s = __fadd_rn(sqq, c.w);
  return __fmaf_rn(-2.0f, dot, s);
}

// fast 5-op distance; |fast - ref| <= ~3.4e-5 on this data range.
__device__ __forceinline__ float fast_d2(float qx, float qy, float qz, float sqq,
                                         float4 c) {
  float dot = __fmaf_rn(qz, c.z, __fmaf_rn(qy, c.y, __fmul_rn(qx, c.x)));
  float s = __fadd_rn(sqq, c.w);
  return __fmaf_rn(-2.0f, dot, s);
}

// order-preserving float->u32 (total order == float compare for non-NaN)
__device__ __forceinline__ unsigned int ord_f32(float d) {
  unsigned int b = __float_as_uint(d);
  return b ^ ((b >> 31) ? 0xFFFFFFFFu : 0x80000000u);
}

// ---- eigen-ratio tail (R11-R14-proven: absmax 0.0 measured) ----
__device__ __forceinline__ double eigen_ratio_tail(
    float cxx, float cyy, float czz, float cxy, float cxz, float cyz,
    float k1) {
  double a   = (double)__fmul_rn(cxx, k1), b = (double)__fmul_rn(cyy, k1);
  double c2  = (double)__fmul_rn(czz, k1);
  double dxy = (double)__fmul_rn(cxy, k1), exz = (double)__fmul_rn(cxz, k1);
  double fyz = (double)__fmul_rn(cyz, k1);
  double qm = (a + b + c2) / 3.0;
  double p1 = dxy * dxy + exz * exz + fyz * fyz;
  double aa = a - qm, bb = b - qm, cc = c2 - qm;
  double p2 = aa * aa + bb * bb + cc * cc + 2.0 * p1;
  if (p2 <= 0.0) return 1.0;
  double p  = sqrt(p2 / 6.0);
  double ip = 1.0 / p;
  double b00 = aa * ip, b11 = bb * ip, b22 = cc * ip;
  double b01 = dxy * ip, b02 = exz * ip, b12 = fyz * ip;
  double detB = b00 * (b11 * b22 - b12 * b12)
              - b01 * (b01 * b22 - b12 * b02)
              + b02 * (b01 * b12 - b11 * b02);
  double r = 0.5 * detB;
  r = fmin(1.0, fmax(-1.0, r));
  const double dcl = 2.0 * r;
  float phif = acosf((float)r) * (1.0f / 3.0f);
  double y0 = 2.0 * (double)cosf(phif);
  double y2 = 2.0 * (double)cosf(phif + 2.0943951f);
#pragma unroll
  for (int it = 0; it < 3; ++it) {
    double g0 = 3.0 * (y0 * y0 - 1.0);
    if (fabs(g0) > 1e-4) y0 -= (y0 * y0 * y0 - 3.0 * y0 - dcl) / g0;
    double g2 = 3.0 * (y2 * y2 - 1.0);
    if (fabs(g2) > 1e-4) y2 -= (y2 * y2 * y2 - 3.0 * y2 - dcl) / g2;
  }
  double e0 = qm + p * y0;
  double e2v = qm + p * y2;
  double e1 = 3.0 * qm - e0 - e2v;
  return e0 / e1;
}

// batched top-16 update: 8 new distances d[0..7] vs sorted-asc bd[0..15]
__device__ __forceinline__ void topk_update(float bd[KK], float d[8]) {
  CSWAP_DESC(d[0], d[1]) CSWAP_DESC(d[2], d[3]) CSWAP_DESC(d[4], d[5]) CSWAP_DESC(d[6], d[7])
  CSWAP_DESC(d[0], d[2]) CSWAP_DESC(d[1], d[3]) CSWAP_DESC(d[4], d[6]) CSWAP_DESC(d[5], d[7])
  CSWAP_DESC(d[1], d[2]) CSWAP_DESC(d[5], d[6])
  CSWAP_DESC(d[0], d[4]) CSWAP_DESC(d[1], d[5]) CSWAP_DESC(d[2], d[6]) CSWAP_DESC(d[3], d[7])
  CSWAP_DESC(d[2], d[4]) CSWAP_DESC(d[3], d[5])
  CSWAP_DESC(d[1], d[2]) CSWAP_DESC(d[3], d[4]) CSWAP_DESC(d[5], d[6])
#pragma unroll
  for (int i = 0; i < 8; ++i) bd[8 + i] = fminf(bd[8 + i], d[i]);
#pragma unroll
  for (int i = 0; i < 8; ++i)  CSWAP_ASC(bd[i], bd[i + 8])
#pragma unroll
  for (int i = 0; i < 4; ++i)  CSWAP_ASC(bd[i], bd[i + 4])
#pragma unroll
  for (int i = 8; i < 12; ++i) CSWAP_ASC(bd[i], bd[i + 4])
#pragma unroll
  for (int g = 0; g < 4; ++g) {
    CSWAP_ASC(bd[4 * g + 0], bd[4 * g + 2]) CSWAP_ASC(bd[4 * g + 1], bd[4 * g + 3])
    CSWAP_ASC(bd[4 * g + 0], bd[4 * g + 1]) CSWAP_ASC(bd[4 * g + 2], bd[4 * g + 3])
  }
}

__global__ void prep_kernel(const float* __restrict__ x,
                            float4* __restrict__ cand) {
  int i = blockIdx.x * 256 + threadIdx.x;
  if (i < NPTS) {
    float px = x[3 * i + 0], py = x[3 * i + 1], pz = x[3 * i + 2];
    cand[i] = make_float4(px, py, pz, ref_sq(px, py, pz));
  }
}

// ---------------- single fused kernel: tau + filter + select + eigen --------
__global__ __launch_bounds__(512, 4) void filter_select_kernel(
    const float4* __restrict__ cand, float* __restrict__ out) {
  extern __shared__ __align__(16) char smem[];
  float4* samp = (float4*)smem;                              // phase 0
  float (*s_t)[64][17] = (float (*)[64][17])(smem + 16384);  // phase 0
  unsigned short* s_idx = (unsigned short*)smem;             // phase 1
  unsigned long long* keys = (unsigned long long*)smem;      // phase 2+
  unsigned short* s_cnt = (unsigned short*)(smem + 70144);   // [8][64]
  float* s_tau = (float*)(smem + 71168);                     // [64]

  const int tid   = threadIdx.x;
  const int lane  = tid & 63;
  const int w     = __builtin_amdgcn_readfirstlane(tid >> 6);
  const int group = blockIdx.x;              // 0..511
  const int batch = group >> 7;
  const int qbase = (group & 127) * QPB;
  const float4* __restrict__ Cb = cand + (size_t)batch * NP;

  const float4 q = Cb[qbase + lane];
  const float qx = q.x, qy = q.y, qz = q.z, sqq = q.w;

  // ---- phase 0: tau = 16th-smallest fast-d over sample [0,1024) ----
  // (verbatim R14 tau stage, inlined; removes a dispatch + tauArr round-trip)
#pragma unroll
  for (int r = 0; r < TSAMP / 512; ++r)
    samp[r * 512 + tid] = Cb[r * 512 + tid];
  __syncthreads();

  {
    float bdA[KK], bdB[KK];
#pragma unroll
    for (int t = 0; t < KK; ++t) { bdA[t] = 3.4e38f; bdB[t] = 3.4e38f; }

    const int j0 = w * TTCH;
    for (int jj = 0; jj < TTCH; jj += 16) {
      float dA[8], dB[8];
      {
        const float4* xp = samp + (j0 + jj);   // uniform LDS addr: broadcast
        float4 c[8];
#pragma unroll
        for (int u = 0; u < 8; ++u) c[u] = xp[u];
#pragma unroll
        for (int u = 0; u < 8; ++u) dA[u] = fast_d2(qx, qy, qz, sqq, c[u]);
      }
      {
        const float4* xp = samp + (j0 + jj + 8);
        float4 c[8];
#pragma unroll
        for (int u = 0; u < 8; ++u) c[u] = xp[u];
#pragma unroll
        for (int u = 0; u < 8; ++u) dB[u] = fast_d2(qx, qy, qz, sqq, c[u]);
      }
      topk_update(bdA, dA);                  // two independent chains
      topk_update(bdB, dB);
    }
    topk_update(bdA, &bdB[0]);               // exact union merge
    topk_update(bdA, &bdB[8]);

#pragma unroll
    for (int t = 0; t < KK; ++t) s_t[w][lane][t] = bdA[t];  // disjoint from samp
  }
  __syncthreads();

  if (w == 0) {                              // wave-uniform merge
    float md[KK];
#pragma unroll
    for (int t = 0; t < KK; ++t) md[t] = s_t[0][lane][t];
#pragma unroll
    for (int s2 = 1; s2 < NBCH; ++s2) {
      float d[KK];
#pragma unroll
      for (int t = 0; t < KK; ++t) d[t] = s_t[s2][lane][t];
      topk_update(md, &d[0]);
      topk_update(md, &d[8]);
    }
    s_tau[lane] = md[KK - 1];
  }
  __syncthreads();                           // s_tau ready; phase-0 reads done

  // ---- phase 1: filter (R14-proven body; fast_d2 vs margined tau) ----
  {
    const int j0 = w * BCH;
    const float tau = s_tau[lane] + TAU_MARGIN;
    unsigned short* Srow = &s_idx[w * SCH + lane * SROW];
    int cnt = 0;
    for (int jj = 0; jj < BCH; jj += 16) {
      const float4* xp = Cb + (j0 + jj);     // wave-uniform address
      float4 c[16];
#pragma unroll
      for (int u = 0; u < 16; ++u) c[u] = xp[u];   // 16 loads in flight
#pragma unroll
      for (int u = 0; u < 16; ++u) {
        float d = fast_d2(qx, qy, qz, sqq, c[u]);
        if (d <= tau) {
          if (cnt < CAP) Srow[1 + cnt] = (unsigned short)(j0 + jj + u);
          ++cnt;                             // count ALL survivors
        }
      }
    }
    s_cnt[w * 64 + lane] = (unsigned short)cnt;
  }
  __syncthreads();

  // ---- phase 2: 8 threads/query; thread (q,p) -> chunk p's top-16 keys ----
  const int qlq = tid >> 3;                  // query-in-group 0..63
  const int pch = tid & 7;                   // source chunk 0..7
  unsigned long long slots[KK];
#pragma unroll
  for (int t = 0; t < KK; ++t) slots[t] = PADKEY;
  {
    const float4 qq = Cb[qbase + qlq];
    const float q2x = qq.x, q2y = qq.y, q2z = qq.z, sq2 = qq.w;
    const unsigned short* row = &s_idx[pch * SCH + qlq * SROW + 1];
    int cnl = (int)s_cnt[pch * 64 + qlq];
    if (cnl > CAP) cnl = CAP;                // overflow query goes fs anyway
    for (int e = 0; e < cnl; e += 8) {
      unsigned long long kv[8];
#pragma unroll
      for (int u = 0; u < 8; ++u) {
        const bool ok = (e + u) < cnl;
        const int j = ok ? (int)row[e + u] : 0;
        const float dd = ref_d2q(q2x, q2y, q2z, sq2, Cb[j]);  // EXACT re-rank
        kv[u] = ok ? ((((unsigned long long)ord_f32(dd)) << 32) |
                      (unsigned int)j)
                   : PADKEY;
      }
#pragma unroll
      for (int u = 0; u < 8; ++u) {
        const unsigned long long k = kv[u];
        if (k < slots[KK - 1]) {
#pragma unroll
          for (int t = KK - 1; t >= 1; --t) {
            unsigned long long lo =
                (slots[t] < k) ? slots[t] : k;           // min
            slots[t] = (slots[t - 1] > lo) ? slots[t - 1] : lo;  // max
          }
          slots[0] = (slots[0] < k) ? slots[0] : k;
        }
      }
    }
  }
  __syncthreads();                           // all s_idx reads complete

  // write keys (overlays s_idx region); padded strides kill bank conflicts
#pragma unroll
  for (int t = 0; t < KK; ++t)
    keys[qlq * KQS + pch * KCH + t] = slots[t];
  __syncthreads();

  // ---- phase 3+4: one thread per query: merge + covariance + eigen ----
  if (tid < QPB) {
    const int ql = tid;
    const int qg = batch * NP + qbase + ql;
    const float4 qq = Cb[qbase + ql];
    const float q2x = qq.x, q2y = qq.y, q2z = qq.z, sq2 = qq.w;

    int total = 0;
    bool fs = false;
#pragma unroll
    for (int p = 0; p < NBCH; ++p) {
      const int c = (int)s_cnt[p * 64 + ql];
      if (c > CAP) fs = true;
      total += c;
    }
    if (total < KK) fs = true;

    int mjr[KK];
    if (!fs) {
      // 8-way tournament merge of sorted key lists; 16 outputs.
      const unsigned long long* kq = keys + ql * KQS;
      int head[NBCH];
#pragma unroll
      for (int p = 0; p < NBCH; ++p) head[p] = 0;
#pragma unroll
      for (int t = 0; t < KK; ++t) {
        unsigned long long best = PADKEY;
        int bp = 0;
#pragma unroll
        for (int p = 0; p < NBCH; ++p) {
          const unsigned long long k =
              (head[p] < KK) ? kq[p * KCH + head[p]] : PADKEY;
          if (k < best) { best = k; bp = p; }
        }
        head[bp]++;
        mjr[t] = (int)(best & 0xFFFFull);    // j (real keys: < 8192)
      }
    } else {
      // exact full-scan insertion with index tracking (verbatim-proven)
      float md[KK];
#pragma unroll
      for (int t = 0; t < KK; ++t) { md[t] = 3.4e38f; mjr[t] = 0; }
      for (int j = 0; j < NP; ++j) {
        float d = ref_d2q(q2x, q2y, q2z, sq2, Cb[j]);
        if (d < md[KK - 1]) {
          bool c0 = d < md[0];
#pragma unroll
          for (int t = KK - 1; t >= 1; --t) {
            bool cl = d < md[t];
            bool cp = d < md[t - 1];
            float nv = fmaxf(md[t - 1], fminf(md[t], d));
            mjr[t] = cl ? (cp ? mjr[t - 1] : j) : mjr[t];
            md[t] = nv;
          }
          mjr[0] = c0 ? j : mjr[0];
          md[0] = fminf(md[0], d);
        }
      }
    }

    // covariance in merged (d,j) order == proven chain order
    float4 pts[KK];
#pragma unroll
    for (int s = 0; s < KK; ++s) pts[s] = Cb[mjr[s]];

    float sx = 0.f, sy = 0.f, sz = 0.f;
#pragma unroll
    for (int s = 0; s < KK; ++s) {
      sx = __fadd_rn(sx, pts[s].x);
      sy = __fadd_rn(sy, pts[s].y);
      sz = __fadd_rn(sz, pts[s].z);
    }
    const float k1 = 1.0f / KK;
    const float mx = sx * k1, my = sy * k1, mz = sz * k1;

    float cxx = 0.f, cxy = 0.f, cxz = 0.f, cyy = 0.f, cyz = 0.f, czz = 0.f;
#pragma unroll
    for (int s = 0; s < KK; ++s) {
      float dx = __fsub_rn(pts[s].x, mx);
      float dy = __fsub_rn(pts[s].y, my);
      float dz = __fsub_rn(pts[s].z, mz);
      cxx = __fadd_rn(cxx, __fmul_rn(dx, dx));
      cxy = __fadd_rn(cxy, __fmul_rn(dx, dy));
      cxz = __fadd_rn(cxz, __fmul_rn(dx, dz));
      cyy = __fadd_rn(cyy, __fmul_rn(dy, dy));
      cyz = __fadd_rn(cyz, __fmul_rn(dy, dz));
      czz = __fadd_rn(czz, __fmul_rn(dz, dz));
    }

    out[qg] = (float)eigen_ratio_tail(cxx, cyy, czz, cxy, cxz, cyz, k1);
  }
}

// ---------------- fallback: verbatim single kernel (proven pass) ------------
__global__ __launch_bounds__(512, 4) void knn_eigen_fallback(
    const float4* __restrict__ cand, float* __restrict__ out) {
  __shared__ unsigned short s_j[8][QPB][18];

  const int tid   = threadIdx.x;
  const int lane  = tid & 63;
  const int w     = __builtin_amdgcn_readfirstlane(tid >> 6);
  const int batch = blockIdx.x >> 7;
  const int qbase = (blockIdx.x & 127) * QPB;
  const int FCH   = NP / 8;   // 1024

  const float4* __restrict__ Cb = cand + (size_t)batch * NP;

  const float4 q = Cb[qbase + lane];
  const float qx = q.x, qy = q.y, qz = q.z, sqq = q.w;

  float bd[KK];
#pragma unroll
  for (int t = 0; t < KK; ++t) bd[t] = 3.4e38f;

  const int j0 = w * FCH;
  for (int jj = 0; jj < FCH; jj += 8) {
    const float4* xp = Cb + (j0 + jj);
    float4 c[8];
#pragma unroll
    for (int u = 0; u < 8; ++u) c[u] = xp[u];
    float d[8];
#pragma unroll
    for (int u = 0; u < 8; ++u) d[u] = ref_d2q(qx, qy, qz, sqq, c[u]);
    topk_update(bd, d);
  }

  const float T = bd[KK - 1];
  int cnt = 0;
  for (int jj = 0; jj < FCH; jj += 8) {
    const float4* xp = Cb + (j0 + jj);
    float4 c[8];
#pragma unroll
    for (int u = 0; u < 8; ++u) c[u] = xp[u];
#pragma unroll
    for (int u = 0; u < 8; ++u) {
      float d = ref_d2q(qx, qy, qz, sqq, c[u]);
      if (d <= T && cnt < KK) {
        s_j[w][lane][cnt] = (unsigned short)(j0 + jj + u);
        cnt++;
      }
    }
  }
  __syncthreads();

  if (tid < QPB) {
    const float4 qq = Cb[qbase + tid];
    const float q2x = qq.x, q2y = qq.y, q2z = qq.z, sq2 = qq.w;
    float md[KK]; int mj[KK];
#pragma unroll
    for (int t = 0; t < KK; ++t) { md[t] = 3.4e38f; mj[t] = 0; }
    for (int cch = 0; cch < 8; ++cch) {
      const unsigned int* rowp = (const unsigned int*)&s_j[cch][tid][0];
#pragma unroll
      for (int sp = 0; sp < KK / 2; ++sp) {
        unsigned int pk = rowp[sp];
#pragma unroll
        for (int half = 0; half < 2; ++half) {
          int j = (half == 0) ? (int)(pk & 0xFFFFu) : (int)(pk >> 16);
          float d = ref_d2q(q2x, q2y, q2z, sq2, Cb[j]);
          if (d < md[KK - 1]) {
            bool c0 = d < md[0];
#pragma unroll
            for (int t = KK - 1; t >= 1; --t) {
              bool cl = d < md[t];
              bool cp = d < md[t - 1];
              float nv = fmaxf(md[t - 1], fminf(md[t], d));
              mj[t] = cl ? (cp ? mj[t - 1] : j) : mj[t];
              md[t] = nv;
            }
            mj[0] = c0 ? j : mj[0];
            md[0] = fminf(md[0], d);
          }
        }
      }
    }
    float sx = 0.f, sy = 0.f, sz = 0.f;
#pragma unroll
    for (int s = 0; s < KK; ++s) {
      float4 pp = Cb[mj[s]];
      sx = __fadd_rn(sx, pp.x);
      sy = __fadd_rn(sy, pp.y);
      sz = __fadd_rn(sz, pp.z);
    }
    const float k1 = 1.0f / KK;
    const float mx = sx * k1, my = sy * k1, mz = sz * k1;
    float cxx = 0.f, cxy = 0.f, cxz = 0.f, cyy = 0.f, cyz = 0.f, czz = 0.f;
#pragma unroll
    for (int s = 0; s < KK; ++s) {
      float4 pp = Cb[mj[s]];
      float dx = __fsub_rn(pp.x, mx);
      float dy = __fsub_rn(pp.y, my);
      float dz = __fsub_rn(pp.z, mz);
      cxx = __fadd_rn(cxx, __fmul_rn(dx, dx));
      cxy = __fadd_rn(cxy, __fmul_rn(dx, dy));
      cxz = __fadd_rn(cxz, __fmul_rn(dx, dz));
      cyy = __fadd_rn(cyy, __fmul_rn(dy, dy));
      cyz = __fadd_rn(cyz, __fmul_rn(dy, dz));
      czz = __fadd_rn(czz, __fmul_rn(dz, dz));
    }
    out[(size_t)batch * NP + qbase + tid] =
        (float)eigen_ratio_tail(cxx, cyy, czz, cxy, cxz, cyz, k1);
  }
}

extern "C" void kernel_launch(void* const* d_in, const int* in_sizes, int n_in,
                              void* d_out, int out_size, void* d_ws, size_t ws_size,
                              hipStream_t stream) {
  const float* x = (const float*)d_in[0];
  float* out = (float*)d_out;
  float4* cand = (float4*)d_ws;                                   // 512 KB
  const size_t need = (size_t)NPTS * sizeof(float4);              // 512 KB

  prep_kernel<<<dim3(NPTS / 256), dim3(256), 0, stream>>>(x, cand);
  if (ws_size >= need) {
    const size_t fs_lds = 71424;   // samp/s_t | s_idx | keys union + s_cnt + s_tau
    filter_select_kernel<<<dim3(512), dim3(512), fs_lds, stream>>>(cand, out);
  } else {
    knn_eigen_fallback<<<dim3(NPTS / QPB), dim3(512), 0, stream>>>(cand, out);
  }
}

// Round 16
// 182.331 us; speedup vs baseline: 1.4316x; 1.0128x over previous
//
#include <hip/hip_runtime.h>
#include <math.h>

#define NB 4
#define NP 8192
#define KK 16
#define QPB 64
#define NPTS (NB * NP)

// ---- geometry (round 16: single dispatch, reads x directly, no workspace) --
#define TSAMP 1024            // tau sample = candidates [0,1024)
#define TTCH 128              // tau subchunk per wave (1024/8)
#define BCH 1024              // filter chunk size
#define NBCH 8                // 8 chunks cover [0,8192)
#define CAP 62                // per-(query,chunk) capacity: P(overflow)~1e-11
#define SROW 66               // u16 per (chunk,query) LDS row (odd dwords: conflict-free)
#define SCH (64 * SROW + 2)   // LDS chunk stride in u16 (=4226)
#define KCH 17                // keys: u64 per chunk-list (16 + 1 pad)
#define KQS (NBCH * KCH + 1)  // keys: u64 per query block (137)
#define PADKEY 0xFFFFFFFFFFFFFFFFull
#define TAU_MARGIN 2.5e-4f    // >= 3x the |diff_d - ref_d| bound (~3.5e-5) x2
// Dynamic LDS (71,424 B):
//   [0,70144)      phase 0: samp float4[768] = raw x sample (12,288B) +
//                           s_t f32[8][64][17] at offset 16384 (34,816B)
//                  phase 1: s_idx u16 8x4226 (67,616B)  -- overlays (barriered)
//                  phase 2+: keys u64[64][137] (70,144B) -- overlays (barriered)
//   [70144,71168)  s_cnt u16[8][64]
//   [71168,71424)  s_tau f32[64]
//
// Correctness chain (fail-safe, independent of tau's value):
//  Filter keeps S = {j: diff_d(j) <= tau + MARGIN}, tau = 16th-smallest
//  diff_d over the 1024-sample. diff-form d=(dx^2+dy^2+dz^2) has error
//  ~ulp-level; |diff_d - ref_d| <= ~3.5e-5 (dominated by ref_d's own
//  cancellation error), so MARGIN 2.5e-4 >= 2x the worst chain and the exact
//  ref top-16 is inside S whenever |S| >= 16. Phase 2 re-ranks S with EXACT
//  ref-rounded distance (c.w = ref_sq inline, bit-identical to the old prep
//  kernel's value); key = (orderable(d)<<32)|j reproduces the proven chain's
//  total order (d asc, j asc) -> identical top-16 in identical order (absmax
//  0.0, R12-R15). Chunk cnt > CAP or total < 16 => in-kernel exact full-scan.

// comparator macros (exact: min/max introduce no rounding)
#define CSWAP_DESC(a, b) { float _lo = fminf(a, b); float _hi = fmaxf(a, b); a = _hi; b = _lo; }
#define CSWAP_ASC(a, b)  { float _lo = fminf(a, b); float _hi = fmaxf(a, b); a = _lo; b = _hi; }

__device__ __forceinline__ float ref_sq(float x, float y, float z) {
  return __fadd_rn(__fadd_rn(__fmul_rn(x, x), __fmul_rn(y, y)), __fmul_rn(z, z));
}

// reference-rounded d2 = (sqq + sqc) - 2*dot (the exact selection metric)
__device__ __forceinline__ float ref_d2(float qx, float qy, float qz, float sqq,
                                        float cx, float cy, float cz) {
  float sqc = ref_sq(cx, cy, cz);
  float dot = __fadd_rn(__fadd_rn(__fmul_rn(qx, cx), __fmul_rn(qy, cy)),
                        __fmul_rn(qz, cz));
  float s = __fadd_rn(sqq, sqc);
  return __fmaf_rn(-2.0f, dot, s);
}

// diff-form distance (6 VALU, near-exact): used for tau + filter only
__device__ __forceinline__ float diff_d2(float qx, float qy, float qz,
                                         float cx, float cy, float cz) {
  float dx = cx - qx, dy = cy - qy, dz = cz - qz;
  return __fmaf_rn(dz, dz, __fmaf_rn(dy, dy, dx * dx));
}

// order-preserving float->u32 (total order == float compare for non-NaN)
__device__ __forceinline__ unsigned int ord_f32(float d) {
  unsigned int b = __float_as_uint(d);
  return b ^ ((b >> 31) ? 0xFFFFFFFFu : 0x80000000u);
}

// ---- eigen-ratio tail (R11-R15-proven: absmax 0.0 measured) ----
__device__ __forceinline__ double eigen_ratio_tail(
    float cxx, float cyy, float czz, float cxy, float cxz, float cyz,
    float k1) {
  double a   = (double)__fmul_rn(cxx, k1), b = (double)__fmul_rn(cyy, k1);
  double c2  = (double)__fmul_rn(czz, k1);
  double dxy = (double)__fmul_rn(cxy, k1), exz = (double)__fmul_rn(cxz, k1);
  double fyz = (double)__fmul_rn(cyz, k1);
  double qm = (a + b + c2) / 3.0;
  double p1 = dxy * dxy + exz * exz + fyz * fyz;
  double aa = a - qm, bb = b - qm, cc = c2 - qm;
  double p2 = aa * aa + bb * bb + cc * cc + 2.0 * p1;
  if (p2 <= 0.0) return 1.0;
  double p  = sqrt(p2 / 6.0);
  double ip = 1.0 / p;
  double b00 = aa * ip, b11 = bb * ip, b22 = cc * ip;
  double b01 = dxy * ip, b02 = exz * ip, b12 = fyz * ip;
  double detB = b00 * (b11 * b22 - b12 * b12)
              - b01 * (b01 * b22 - b12 * b02)
              + b02 * (b01 * b12 - b11 * b02);
  double r = 0.5 * detB;
  r = fmin(1.0, fmax(-1.0, r));
  const double dcl = 2.0 * r;
  float phif = acosf((float)r) * (1.0f / 3.0f);
  double y0 = 2.0 * (double)cosf(phif);
  double y2 = 2.0 * (double)cosf(phif + 2.0943951f);
#pragma unroll
  for (int it = 0; it < 3; ++it) {
    double g0 = 3.0 * (y0 * y0 - 1.0);
    if (fabs(g0) > 1e-4) y0 -= (y0 * y0 * y0 - 3.0 * y0 - dcl) / g0;
    double g2 = 3.0 * (y2 * y2 - 1.0);
    if (fabs(g2) > 1e-4) y2 -= (y2 * y2 * y2 - 3.0 * y2 - dcl) / g2;
  }
  double e0 = qm + p * y0;
  double e2v = qm + p * y2;
  double e1 = 3.0 * qm - e0 - e2v;
  return e0 / e1;
}

// batched top-16 update: 8 new distances d[0..7] vs sorted-asc bd[0..15]
__device__ __forceinline__ void topk_update(float bd[KK], float d[8]) {
  CSWAP_DESC(d[0], d[1]) CSWAP_DESC(d[2], d[3]) CSWAP_DESC(d[4], d[5]) CSWAP_DESC(d[6], d[7])
  CSWAP_DESC(d[0], d[2]) CSWAP_DESC(d[1], d[3]) CSWAP_DESC(d[4], d[6]) CSWAP_DESC(d[5], d[7])
  CSWAP_DESC(d[1], d[2]) CSWAP_DESC(d[5], d[6])
  CSWAP_DESC(d[0], d[4]) CSWAP_DESC(d[1], d[5]) CSWAP_DESC(d[2], d[6]) CSWAP_DESC(d[3], d[7])
  CSWAP_DESC(d[2], d[4]) CSWAP_DESC(d[3], d[5])
  CSWAP_DESC(d[1], d[2]) CSWAP_DESC(d[3], d[4]) CSWAP_DESC(d[5], d[6])
#pragma unroll
  for (int i = 0; i < 8; ++i) bd[8 + i] = fminf(bd[8 + i], d[i]);
#pragma unroll
  for (int i = 0; i < 8; ++i)  CSWAP_ASC(bd[i], bd[i + 8])
#pragma unroll
  for (int i = 0; i < 4; ++i)  CSWAP_ASC(bd[i], bd[i + 4])
#pragma unroll
  for (int i = 8; i < 12; ++i) CSWAP_ASC(bd[i], bd[i + 4])
#pragma unroll
  for (int g = 0; g < 4; ++g) {
    CSWAP_ASC(bd[4 * g + 0], bd[4 * g + 2]) CSWAP_ASC(bd[4 * g + 1], bd[4 * g + 3])
    CSWAP_ASC(bd[4 * g + 0], bd[4 * g + 1]) CSWAP_ASC(bd[4 * g + 2], bd[4 * g + 3])
  }
}

// ---------------- single fused kernel: tau + filter + select + eigen --------
// Reads x (packed float3) directly; no prep, no workspace, one dispatch.
__global__ __launch_bounds__(512, 4) void filter_select_kernel(
    const float* __restrict__ x, float* __restrict__ out) {
  extern __shared__ __align__(16) char smem[];
  float4* samp = (float4*)smem;                              // phase 0 (12.3KB)
  float (*s_t)[64][17] = (float (*)[64][17])(smem + 16384);  // phase 0
  unsigned short* s_idx = (unsigned short*)smem;             // phase 1
  unsigned long long* keys = (unsigned long long*)smem;      // phase 2+
  unsigned short* s_cnt = (unsigned short*)(smem + 70144);   // [8][64]
  float* s_tau = (float*)(smem + 71168);                     // [64]

  const int tid   = threadIdx.x;
  const int lane  = tid & 63;
  const int w     = __builtin_amdgcn_readfirstlane(tid >> 6);
  const int group = blockIdx.x;              // 0..511
  const int batch = group >> 7;
  const int qbase = (group & 127) * QPB;
  const float* __restrict__ Xb = x + (size_t)batch * NP * 3;

  const float qx = Xb[3 * (qbase + lane) + 0];
  const float qy = Xb[3 * (qbase + lane) + 1];
  const float qz = Xb[3 * (qbase + lane) + 2];
  const float sqq = ref_sq(qx, qy, qz);      // bit-identical to old prep's .w

  // ---- phase 0: tau = 16th-smallest diff-d over sample [0,1024) ----
  // stage raw x sample (768 float4 = 1024 points) into LDS
  {
    const float4* X4 = (const float4*)Xb;    // batch base is 16B-aligned
#pragma unroll
    for (int r = 0; r < 2; ++r) {
      const int idx = r * 512 + tid;
      if (idx < (TSAMP * 3) / 4) samp[idx] = X4[idx];
    }
  }
  __syncthreads();

  {
    const float* sf = (const float*)samp;
    float bdA[KK], bdB[KK];
#pragma unroll
    for (int t = 0; t < KK; ++t) { bdA[t] = 3.4e38f; bdB[t] = 3.4e38f; }

    const int j0 = w * TTCH;
    for (int jj = 0; jj < TTCH; jj += 16) {
      float dA[8], dB[8];
#pragma unroll
      for (int u = 0; u < 8; ++u) {
        const int j = 3 * (j0 + jj + u);     // uniform LDS addr: broadcast
        dA[u] = diff_d2(qx, qy, qz, sf[j], sf[j + 1], sf[j + 2]);
      }
#pragma unroll
      for (int u = 0; u < 8; ++u) {
        const int j = 3 * (j0 + jj + 8 + u);
        dB[u] = diff_d2(qx, qy, qz, sf[j], sf[j + 1], sf[j + 2]);
      }
      topk_update(bdA, dA);                  // two independent chains
      topk_update(bdB, dB);
    }
    topk_update(bdA, &bdB[0]);               // exact union merge
    topk_update(bdA, &bdB[8]);

#pragma unroll
    for (int t = 0; t < KK; ++t) s_t[w][lane][t] = bdA[t];  // disjoint region
  }
  __syncthreads();

  if (w == 0) {                              // wave-uniform merge
    float md[KK];
#pragma unroll
    for (int t = 0; t < KK; ++t) md[t] = s_t[0][lane][t];
#pragma unroll
    for (int s2 = 1; s2 < NBCH; ++s2) {
      float d[KK];
#pragma unroll
      for (int t = 0; t < KK; ++t) d[t] = s_t[s2][lane][t];
      topk_update(md, &d[0]);
      topk_update(md, &d[8]);
    }
    s_tau[lane] = md[KK - 1];
  }
  __syncthreads();                           // s_tau ready; phase-0 reads done

  // ---- phase 1: filter (diff-d vs margined tau; 12 float4 per 16 cands) ----
  {
    const int j0 = w * BCH;
    const float tau = s_tau[lane] + TAU_MARGIN;
    unsigned short* Srow = &s_idx[w * SCH + lane * SROW];
    int cnt = 0;
    for (int jj = 0; jj < BCH; jj += 16) {
      const float4* xp = (const float4*)(Xb + (size_t)(j0 + jj) * 3);
      float4 cv[12];
#pragma unroll
      for (int u = 0; u < 12; ++u) cv[u] = xp[u];  // 12 loads in flight
      const float* f = (const float*)cv;           // static idx: reg aliasing
#pragma unroll
      for (int u = 0; u < 16; ++u) {
        float d = diff_d2(qx, qy, qz, f[3 * u], f[3 * u + 1], f[3 * u + 2]);
        if (d <= tau) {
          if (cnt < CAP) Srow[1 + cnt] = (unsigned short)(j0 + jj + u);
          ++cnt;                             // count ALL survivors
        }
      }
    }
    s_cnt[w * 64 + lane] = (unsigned short)cnt;
  }
  __syncthreads();

  // ---- phase 2: 8 threads/query; thread (q,p) -> chunk p's top-16 keys ----
  const int qlq = tid >> 3;                  // query-in-group 0..63
  const int pch = tid & 7;                   // source chunk 0..7
  unsigned long long slots[KK];
#pragma unroll
  for (int t = 0; t < KK; ++t) slots[t] = PADKEY;
  {
    const float q2x = Xb[3 * (qbase + qlq) + 0];
    const float q2y = Xb[3 * (qbase + qlq) + 1];
    const float q2z = Xb[3 * (qbase + qlq) + 2];
    const float sq2 = ref_sq(q2x, q2y, q2z);
    const unsigned short* row = &s_idx[pch * SCH + qlq * SROW + 1];
    int cnl = (int)s_cnt[pch * 64 + qlq];
    if (cnl > CAP) cnl = CAP;                // overflow query goes fs anyway
    for (int e = 0; e < cnl; e += 8) {
      unsigned long long kv[8];
#pragma unroll
      for (int u = 0; u < 8; ++u) {
        const bool ok = (e + u) < cnl;
        const int j = ok ? (int)row[e + u] : 0;
        const float cx = Xb[3 * j], cy = Xb[3 * j + 1], cz = Xb[3 * j + 2];
        const float dd = ref_d2(q2x, q2y, q2z, sq2, cx, cy, cz);  // EXACT
        kv[u] = ok ? ((((unsigned long long)ord_f32(dd)) << 32) |
                      (unsigned int)j)
                   : PADKEY;
      }
#pragma unroll
      for (int u = 0; u < 8; ++u) {
        const unsigned long long k = kv[u];
        if (k < slots[KK - 1]) {
#pragma unroll
          for (int t = KK - 1; t >= 1; --t) {
            unsigned long long lo =
                (slots[t] < k) ? slots[t] : k;           // min
            slots[t] = (slots[t - 1] > lo) ? slots[t - 1] : lo;  // max
          }
          slots[0] = (slots[0] < k) ? slots[0] : k;
        }
      }
    }
  }
  __syncthreads();                           // all s_idx reads complete

  // write keys (overlays s_idx region); padded strides kill bank conflicts
#pragma unroll
  for (int t = 0; t < KK; ++t)
    keys[qlq * KQS + pch * KCH + t] = slots[t];
  __syncthreads();

  // ---- phase 3+4: one thread per query: merge + covariance + eigen ----
  if (tid < QPB) {
    const int ql = tid;
    const int qg = batch * NP + qbase + ql;
    const float q2x = Xb[3 * (qbase + ql) + 0];
    const float q2y = Xb[3 * (qbase + ql) + 1];
    const float q2z = Xb[3 * (qbase + ql) + 2];
    const float sq2 = ref_sq(q2x, q2y, q2z);

    int total = 0;
    bool fs = false;
#pragma unroll
    for (int p = 0; p < NBCH; ++p) {
      const int c = (int)s_cnt[p * 64 + ql];
      if (c > CAP) fs = true;
      total += c;
    }
    if (total < KK) fs = true;

    int mjr[KK];
    if (!fs) {
      // 8-way tournament merge of sorted key lists; 16 outputs.
      const unsigned long long* kq = keys + ql * KQS;
      int head[NBCH];
#pragma unroll
      for (int p = 0; p < NBCH; ++p) head[p] = 0;
#pragma unroll
      for (int t = 0; t < KK; ++t) {
        unsigned long long best = PADKEY;
        int bp = 0;
#pragma unroll
        for (int p = 0; p < NBCH; ++p) {
          const unsigned long long k =
              (head[p] < KK) ? kq[p * KCH + head[p]] : PADKEY;
          if (k < best) { best = k; bp = p; }
        }
        head[bp]++;
        mjr[t] = (int)(best & 0xFFFFull);    // j (real keys: < 8192)
      }
    } else {
      // exact full-scan insertion with index tracking (verbatim-proven)
      float md[KK];
#pragma unroll
      for (int t = 0; t < KK; ++t) { md[t] = 3.4e38f; mjr[t] = 0; }
      for (int j = 0; j < NP; ++j) {
        float d = ref_d2(q2x, q2y, q2z, sq2,
                         Xb[3 * j], Xb[3 * j + 1], Xb[3 * j + 2]);
        if (d < md[KK - 1]) {
          bool c0 = d < md[0];
#pragma unroll
          for (int t = KK - 1; t >= 1; --t) {
            bool cl = d < md[t];
            bool cp = d < md[t - 1];
            float nv = fmaxf(md[t - 1], fminf(md[t], d));
            mjr[t] = cl ? (cp ? mjr[t - 1] : j) : mjr[t];
            md[t] = nv;
          }
          mjr[0] = c0 ? j : mjr[0];
          md[0] = fminf(md[0], d);
        }
      }
    }

    // covariance in merged (d,j) order == proven chain order
    float px[KK], py[KK], pz[KK];
#pragma unroll
    for (int s = 0; s < KK; ++s) {
      px[s] = Xb[3 * mjr[s]];
      py[s] = Xb[3 * mjr[s] + 1];
      pz[s] = Xb[3 * mjr[s] + 2];
    }

    float sx = 0.f, sy = 0.f, sz = 0.f;
#pragma unroll
    for (int s = 0; s < KK; ++s) {
      sx = __fadd_rn(sx, px[s]);
      sy = __fadd_rn(sy, py[s]);
      sz = __fadd_rn(sz, pz[s]);
    }
    const float k1 = 1.0f / KK;
    const float mx = sx * k1, my = sy * k1, mz = sz * k1;

    float cxx = 0.f, cxy = 0.f, cxz = 0.f, cyy = 0.f, cyz = 0.f, czz = 0.f;
#pragma unroll
    for (int s = 0; s < KK; ++s) {
      float dx = __fsub_rn(px[s], mx);
      float dy = __fsub_rn(py[s], my);
      float dz = __fsub_rn(pz[s], mz);
      cxx = __fadd_rn(cxx, __fmul_rn(dx, dx));
      cxy = __fadd_rn(cxy, __fmul_rn(dx, dy));
      cxz = __fadd_rn(cxz, __fmul_rn(dx, dz));
      cyy = __fadd_rn(cyy, __fmul_rn(dy, dy));
      cyz = __fadd_rn(cyz, __fmul_rn(dy, dz));
      czz = __fadd_rn(czz, __fmul_rn(dz, dz));
    }

    out[qg] = (float)eigen_ratio_tail(cxx, cyy, czz, cxy, cxz, cyz, k1);
  }
}

extern "C" void kernel_launch(void* const* d_in, const int* in_sizes, int n_in,
                              void* d_out, int out_size, void* d_ws, size_t ws_size,
                              hipStream_t stream) {
  const float* x = (const float*)d_in[0];
  float* out = (float*)d_out;
  const size_t fs_lds = 71424;   // samp/s_t | s_idx | keys union + s_cnt + s_tau
  filter_select_kernel<<<dim3(512), dim3(512), fs_lds, stream>>>(x, out);
}